// Round 6
// baseline (9540.855 us; speedup 1.0000x reference)
//
#include <hip/hip_runtime.h>

typedef _Float16 f16;
typedef _Float16 f16x8 __attribute__((ext_vector_type(8)));
typedef float f32x4 __attribute__((ext_vector_type(4)));
typedef unsigned short ushort_t;

// ---------------------------------------------------------------------------
// PoseConvLSTM via implicit-GEMM MFMA.
//
// Round 6: persistent kernel with a HAND-ROLLED grid barrier (no cooperative
// API). Round 5's cg::grid.sync() version failed on the first call; two
// suspects: (a) unchecked hipLaunchCooperativeKernel failure -> kernel never
// ran (pose==0 matches absmax 3.16), (b) grid.sync lacking cross-XCD
// visibility for plain loads/stores. Both are eliminated here:
//   - normal <<<512,256>>> launch (co-residency by arithmetic:
//     __launch_bounds__(256,2) => VGPR<=256, LDS 29.7KB => >=2 blocks/CU,
//     512 = 256 CUs x 2; nothing else runs on the device)
//   - explicit barrier: leader does __threadfence_system() (release: wbl2
//     flush of this XCD's L2) -> system-scope atomic arrive -> spin on
//     generation -> __threadfence_system() (acquire: invalidate caches).
//   - barrier state in the memset-zeroed ws region; generation is monotonic
//     and only compared by equality => safe across graph replays.
//
// Temporal skew kept: per iteration, blocks 0-255 = L1[t], 256-511 = L2[t-1].
// Numerics identical to round 4 (weights split hi/lo, inputs plain f16,
// 2 MFMA per product; absmax 1.56e-2 vs 6.3e-2 threshold).
//
// Buffers (ws, f16 bits), XCD-safe single-writer-role split:
//   in1[parity]:  [66][66][48]  x[t] c0-2, h1prev c3-34, 0 c35-47 (L1-written)
//   in2a[parity]: [66][66][32]  h1[t]   (L1-written only)
//   in2b[parity]: [66][66][64]  h2[t-1] (L2-written only)
//
// d_out (floats): pose[768] | h1[131072] | c1[131072] | h2[262144] | c2[262144]
// ---------------------------------------------------------------------------

#define IN1SZ 209088    // 66*66*48
#define IN2ASZ 139392   // 66*66*32
#define IN2BSZ 278784   // 66*66*64
#define BAROFF 1254528  // ushort offset of barrier block (2*IN1SZ+2*IN2ASZ+2*IN2BSZ)
#define WP1OFF 1254784  // BAROFF + 256 ushorts (512B barrier slot, memset'd)
#define WP1SZ 147456    // 2mb*18s*4mt*2hl*512
#define WP2OFF (WP1OFF + WP1SZ)
#define WP2SZ 442368    // 2mb*27s*8mt*2hl*512
#define NBLOCKS 512

__device__ __forceinline__ float sigm(float x) {
  return __builtin_amdgcn_rcpf(1.0f + __expf(-x));
}
__device__ __forceinline__ float tanh_fast(float x) {
  float xc = fminf(fmaxf(x, -10.f), 10.f);
  float e = __expf(2.f * xc);
  return (e - 1.f) * __builtin_amdgcn_rcpf(e + 1.f);
}
__device__ __forceinline__ ushort_t f2u(f16 v) { return __builtin_bit_cast(ushort_t, v); }
__device__ __forceinline__ f16x8 u2f(uint4 v) { return __builtin_bit_cast(f16x8, v); }

// ---- explicit grid barrier: release-fence, arrive, spin on generation ----
// cnt/gen in device memory (zeroed by host memset each call). Every block
// calls this exactly once per iteration; leader thread handles the protocol.
__device__ __forceinline__ void grid_barrier(int* cnt, int* gen) {
  __syncthreads();  // all block stores issued+drained (compiler drains vmcnt)
  if (threadIdx.x == 0) {
    __threadfence_system();  // release: write back this XCD's dirty L2
    int g = __hip_atomic_load(gen, __ATOMIC_RELAXED, __HIP_MEMORY_SCOPE_SYSTEM);
    int arrived =
        __hip_atomic_fetch_add(cnt, 1, __ATOMIC_ACQ_REL, __HIP_MEMORY_SCOPE_SYSTEM);
    if (arrived == NBLOCKS - 1) {
      __hip_atomic_store(cnt, 0, __ATOMIC_RELAXED, __HIP_MEMORY_SCOPE_SYSTEM);
      __hip_atomic_fetch_add(gen, 1, __ATOMIC_ACQ_REL, __HIP_MEMORY_SCOPE_SYSTEM);
    } else {
      while (__hip_atomic_load(gen, __ATOMIC_RELAXED, __HIP_MEMORY_SCOPE_SYSTEM) == g) {
        __builtin_amdgcn_s_sleep(4);
      }
    }
    __threadfence_system();  // acquire: invalidate caches, refetch fresh state
  }
  __syncthreads();
}

// ---- init: pack weights (hi/lo) into fragment order, pose=fc_b, stage x[0] ----
__global__ __launch_bounds__(256) void pack_kernel(const float* __restrict__ w1,
                                                   const float* __restrict__ w2,
                                                   const float* __restrict__ fcb,
                                                   const float* __restrict__ x0,
                                                   float* __restrict__ pose,
                                                   ushort_t* __restrict__ wp1,
                                                   ushort_t* __restrict__ wp2,
                                                   ushort_t* __restrict__ in1hi0) {
  int i = blockIdx.x * 256 + threadIdx.x;
  if (i < 55296) {  // wp2: thread per (f, hl, lane), 8 elems each
    int lane = i & 63;
    int r0 = i >> 6;        // [0, 864)
    int hl = r0 & 1;
    int f = r0 >> 1;        // [0, 432) = (mb*27+s)*8+mt
    int mt = f & 7;
    int sm = f >> 3;        // [0,54)
    int s = sm % 27, mb = sm / 27;
    int m = mt * 16 + (lane & 15);
    int rg = mb * 128 + m;
    int h = rg >> 2, G = rg & 3;
    int orow = G * 64 + h;
    int tap = s / 3, cb = (s % 3) * 32;
    int cq = cb + (lane >> 4) * 8;
    for (int j = 0; j < 8; ++j) {
      float v = w2[(orow * 96 + cq + j) * 9 + tap];
      f16 vh = (f16)v;
      f16 vl = (f16)(v - (float)vh);
      wp2[(f * 2 + hl) * 512 + lane * 8 + j] = f2u(hl ? vl : vh);
    }
    return;
  }
  i -= 55296;
  if (i < 18432) {  // wp1
    int lane = i & 63;
    int r0 = i >> 6;        // [0,288)
    int hl = r0 & 1;
    int f = r0 >> 1;        // [0,144) = (mb*18+s)*4+mt
    int mt = f & 3;
    int sm = f >> 2;        // [0,36)
    int s = sm % 18, mb = sm / 18;
    int m = mt * 16 + (lane & 15);
    int rg = mb * 64 + m;
    int h = rg >> 2, G = rg & 3;
    int orow = G * 32 + h;
    int tap = s >> 1, cb = (s & 1) * 32;
    int cq = cb + (lane >> 4) * 8;
    for (int j = 0; j < 8; ++j) {
      int c = cq + j;
      float v = (c < 35) ? w1[(orow * 35 + c) * 9 + tap] : 0.f;
      f16 vh = (f16)v;
      f16 vl = (f16)(v - (float)vh);
      wp1[(f * 2 + hl) * 512 + lane * 8 + j] = f2u(hl ? vl : vh);
    }
    return;
  }
  i -= 18432;
  if (i < 768) { pose[i] = fcb[i % 6]; return; }
  i -= 768;
  if (i < 12288) {  // x[0] -> in1[0] c0-2 (hi only)
    int c = i >> 12, pix = i & 4095;
    int y = pix >> 6, x = pix & 63;
    int pidx = ((y + 1) * 66 + (x + 1)) * 48 + c;
    in1hi0[pidx] = f2u((f16)x0[i]);
  }
}

// ---- one ConvLSTM step for one layer (device body) ----
// bid in [0,256) = 2 M-blocks x 128 pixel tiles (4y x 8x); block 256 = 4 waves.
// L1: input = bhi (in1, 48ch). Writes d1 = in1-next (h1@c3 + x@c0), d2 = in2a.
// L2: input = bhi (in2a, 32ch) + b2hi (in2b, 64ch). Writes d1 = in2b.
template <int LAYER>
__device__ __forceinline__ void conv_body(
    int bid,
    const ushort_t* __restrict__ bhi, const ushort_t* __restrict__ b2hi,
    const ushort_t* __restrict__ wp, const float* __restrict__ bias,
    float* __restrict__ cst, float* __restrict__ hout,              // fp32 c (in-place), h
    ushort_t* __restrict__ d1hi,                                    // primary dest
    ushort_t* __restrict__ d2hi,                                    // secondary (L1 only)
    const float* __restrict__ fcw, float* __restrict__ pose_t,      // L2 only
    const float* __restrict__ xn,                                   // L1 only: x[t+1]
    ushort_t* Bh, float* zs, float (*red)[6]) {
  constexpr int CS = (LAYER == 1) ? 72 : 104;   // LDS c-stride (bank-conflict pad)
  constexpr int NC32 = (LAYER == 1) ? 2 : 3;    // 32-channel chunks
  constexpr int NS = 9 * NC32;                  // k32 steps
  constexpr int MT = (LAYER == 1) ? 4 : 8;      // 16-row m-tiles per block
  constexpr int MTPW = (LAYER == 1) ? 1 : 2;    // m-tiles per wave
  constexpr int H = (LAYER == 1) ? 32 : 64;
  constexpr int ZS = 33;                        // z LDS stride (pad)
  constexpr int D1S = (LAYER == 1) ? 48 : 64;   // primary dest c-stride
  constexpr int D1O = (LAYER == 1) ? 3 : 0;     // primary dest c-offset
  constexpr int DEPTH = 5;                      // A-frag register ring
  constexpr int PRE = DEPTH - 1;

  const int tid = threadIdx.x;
  const int lane = tid & 63;
  const int w = tid >> 6;
  const int mb = bid & 1;
  const int ntile = bid >> 1;
  const int Y0 = (ntile >> 3) * 4;
  const int X0 = (ntile & 7) * 8;

  // ---- A-frag register ring (weight hi+lo): issue loads EARLY ----
  const ushort_t* aptr[MTPW];
#pragma unroll
  for (int m = 0; m < MTPW; ++m) {
    int f = (mb * NS) * MT + (w * MTPW + m);
    aptr[m] = wp + f * 1024 + lane * 8;
  }
  uint4 A[DEPTH][MTPW][2];
  auto loada = [&](int s) {
#pragma unroll
    for (int m = 0; m < MTPW; ++m) {
      const ushort_t* p = aptr[m] + (size_t)s * (MT * 1024);
      A[s % DEPTH][m][0] = *(const uint4*)(p);
      A[s % DEPTH][m][1] = *(const uint4*)(p + 512);
    }
  };
#pragma unroll
  for (int s = 0; s < PRE; ++s) loada(s);

  // ---- stage halo slab [6y][10x][C] into LDS (f16 hi only) ----
  if (LAYER == 2) {
    for (int i = tid; i < 720; i += 256) {
      int hy = i / 120, rem = i % 120;
      int hx = rem / 12, c8 = rem % 12;
      int pos = (Y0 + hy) * 66 + X0 + hx;
      int dst = (hy * 10 + hx) * CS + c8 * 8;
      if (c8 < 4) {  // c0-31 from in2a (h1)
        *(uint4*)(&Bh[dst]) = *(const uint4*)(&bhi[pos * 32 + c8 * 8]);
      } else {       // c32-95 from in2b (h2)
        *(uint4*)(&Bh[dst]) = *(const uint4*)(&b2hi[pos * 64 + (c8 - 4) * 8]);
      }
    }
  } else {
    for (int i = tid; i < 360; i += 256) {
      int hy = i / 60, rem = i % 60;
      int hx = rem / 6, c8 = (rem % 6) * 8;
      int src = ((Y0 + hy) * 66 + X0 + hx) * 48 + c8;
      int dst = (hy * 10 + hx) * CS + c8;
      *(uint4*)(&Bh[dst]) = *(const uint4*)(&bhi[src]);
    }
    for (int i = tid; i < 120; i += 256) {  // zero-pad c 48..63 (read by frags)
      int hp = i >> 1;
      int dst = hp * CS + 48 + (i & 1) * 8;
      *(uint4*)(&Bh[dst]) = uint4{0, 0, 0, 0};
    }
  }
  __syncthreads();

  // ---- K-loop: A frags from registers (ring-prefetched), B frags from LDS ----
  const int n = lane & 15;
  const int q = lane >> 4;
  const int py = n >> 3, px = n & 7;

  f32x4 acc[MTPW][2];
#pragma unroll
  for (int m = 0; m < MTPW; ++m)
#pragma unroll
    for (int nt = 0; nt < 2; ++nt) acc[m][nt] = f32x4{0.f, 0.f, 0.f, 0.f};

#pragma unroll
  for (int s = 0; s < NS; ++s) {
    // rolling prefetch: writes ring slot consumed LAST iteration (WAR-bounded)
    if (s + PRE < NS) loada(s + PRE);
    const int tap = s / NC32, cc = s % NC32;
    const int ty = tap / 3, tx = tap % 3;
    const int coff = cc * 32 + q * 8;
    f16x8 bfh[2];
#pragma unroll
    for (int nt = 0; nt < 2; ++nt) {
      int hp = (py + nt * 2 + ty) * 10 + (px + tx);
      bfh[nt] = u2f(*(const uint4*)(&Bh[hp * CS + coff]));
    }
#pragma unroll
    for (int m = 0; m < MTPW; ++m) {
      f16x8 ah = u2f(A[s % DEPTH][m][0]);
      f16x8 al = u2f(A[s % DEPTH][m][1]);
#pragma unroll
      for (int nt = 0; nt < 2; ++nt) {
        acc[m][nt] = __builtin_amdgcn_mfma_f32_16x16x32_f16(ah, bfh[nt], acc[m][nt], 0, 0, 0);
        acc[m][nt] = __builtin_amdgcn_mfma_f32_16x16x32_f16(al, bfh[nt], acc[m][nt], 0, 0, 0);
      }
    }
  }

  // ---- z exchange through LDS ----
  __syncthreads();
#pragma unroll
  for (int m = 0; m < MTPW; ++m) {
    int mt = w * MTPW + m;
#pragma unroll
    for (int nt = 0; nt < 2; ++nt)
#pragma unroll
      for (int i = 0; i < 4; ++i) zs[(mt * 16 + q * 4 + i) * ZS + nt * 16 + n] = acc[m][nt][i];
  }
  __syncthreads();

  // ---- LSTM cell + state writes (+ FC fuse for L2) ----
  constexpr int NCELL = (MT * 4 * 32) / 256;  // cells per thread (L2: 4, L1: 2)
  float p6[6] = {0, 0, 0, 0, 0, 0};
#pragma unroll
  for (int i = 0; i < NCELL; ++i) {
    int idx = i * 256 + tid;
    int ch = idx >> 5, pI = idx & 31;
    float zi = zs[(ch * 4 + 0) * ZS + pI];
    float zf = zs[(ch * 4 + 1) * ZS + pI];
    float zo = zs[(ch * 4 + 2) * ZS + pI];
    float zg = zs[(ch * 4 + 3) * ZS + pI];
    int hg = mb * (MT * 4) + ch;
    zi += bias[0 * H + hg];
    zf += bias[1 * H + hg];
    zo += bias[2 * H + hg];
    zg += bias[3 * H + hg];
    int y = Y0 + (pI >> 3), x = X0 + (pI & 7);
    int cidx = hg * 4096 + y * 64 + x;
    float cold = cst[cidx];
    float cn = sigm(zf) * cold + sigm(zi) * tanh_fast(zg);
    float hn = sigm(zo) * tanh_fast(cn);
    cst[cidx] = cn;
    hout[cidx] = hn;
    f16 hh = (f16)hn;
    int pidx = (y + 1) * 66 + (x + 1);
    d1hi[pidx * D1S + D1O + hg] = f2u(hh);
    if (LAYER == 1) {
      d2hi[pidx * 32 + hg] = f2u(hh);   // in2a: h1, 32-ch stride
    } else {
#pragma unroll
      for (int j = 0; j < 6; ++j) p6[j] += hn * fcw[j * 262144 + cidx];
    }
  }

  if (LAYER == 2) {
#pragma unroll
    for (int j = 0; j < 6; ++j)
#pragma unroll
      for (int off = 32; off > 0; off >>= 1) p6[j] += __shfl_xor(p6[j], off, 64);
    if (lane == 0)
#pragma unroll
      for (int j = 0; j < 6; ++j) red[w][j] = p6[j];
    __syncthreads();
    if (tid < 6) atomicAdd(pose_t + tid, red[0][tid] + red[1][tid] + red[2][tid] + red[3][tid]);
  } else {
    // stage x[t+1] into in1 next-parity (c0-2); d1 is in1-next
    if (mb == 0 && tid < 32) {
      int y = Y0 + (tid >> 3), x = X0 + (tid & 7);
      int pidx = (y + 1) * 66 + (x + 1);
#pragma unroll
      for (int c = 0; c < 3; ++c) {
        d1hi[pidx * 48 + c] = f2u((f16)xn[c * 4096 + y * 64 + x]);
      }
    }
  }
}

// ---- persistent kernel: t-loop inside, explicit grid barrier per step ----
// blocks 0-255 = L1[t], 256-511 = L2[t-1]; 512 blocks = 2/CU exactly.
__global__ __launch_bounds__(256, 2) void persist_kernel(
    ushort_t* __restrict__ in1_0, ushort_t* __restrict__ in1_1,
    ushort_t* __restrict__ i2a_0, ushort_t* __restrict__ i2a_1,
    ushort_t* __restrict__ i2b_0, ushort_t* __restrict__ i2b_1,
    const ushort_t* __restrict__ wp1, const ushort_t* __restrict__ wp2,
    const float* __restrict__ b1, const float* __restrict__ b2,
    float* __restrict__ c1o, float* __restrict__ h1o,
    float* __restrict__ c2o, float* __restrict__ h2o,
    const float* __restrict__ fcw, float* __restrict__ pose,
    const float* __restrict__ input, int* __restrict__ bar) {
  // union'd shared memory: max over both roles (L2 sizes), ~29.5 KB -> 2/CU
  __shared__ __align__(16) ushort_t Bh[6240];   // max(60*72, 60*104)
  __shared__ float zs[4224];                    // max(64,128)*33
  __shared__ float red[4][6];

  const int bid = blockIdx.x;
  int* cnt = bar;        // zeroed by host memset each call
  int* gen = bar + 64;   // 256B apart
  ushort_t* in1[2] = {in1_0, in1_1};
  ushort_t* i2a[2] = {i2a_0, i2a_1};
  ushort_t* i2b[2] = {i2b_0, i2b_1};

  for (int t = 0; t <= 128; ++t) {
    const int p = t & 1, pn = p ^ 1;
    if (bid < 256) {
      if (t < 128) {
        int tn = (t + 1 < 128) ? t + 1 : 127;
        conv_body<1>(bid, in1[p], nullptr, wp1, b1, c1o, h1o,
                     in1[pn],               // h1 -> in1 next @c3 (+ x[t+1] @c0-2)
                     i2a[p],                // h1 -> in2a[t&1]
                     nullptr, nullptr,
                     input + (size_t)tn * 12288, Bh, zs, red);
      }
    } else {
      if (t >= 1) {
        conv_body<2>(bid - 256, i2a[pn], i2b[pn], wp2, b2, c2o, h2o,
                     i2b[p],                // h2 -> in2b[t&1]
                     nullptr,
                     fcw, pose + (t - 1) * 6, nullptr, Bh, zs, red);
      }
    }
    grid_barrier(cnt, gen);  // release/arrive/spin/acquire across all XCDs
  }
}

extern "C" void kernel_launch(void* const* d_in, const int* in_sizes, int n_in, void* d_out,
                              int out_size, void* d_ws, size_t ws_size, hipStream_t stream) {
  const float* input = (const float*)d_in[0];
  const float* w1 = (const float*)d_in[1];
  const float* b1 = (const float*)d_in[2];
  const float* w2 = (const float*)d_in[3];
  const float* b2 = (const float*)d_in[4];
  const float* fcw = (const float*)d_in[5];
  const float* fcb = (const float*)d_in[6];

  float* out = (float*)d_out;
  float* pose = out;
  float* h1o = out + 768;
  float* c1o = h1o + 131072;
  float* h2o = c1o + 131072;
  float* c2o = h2o + 262144;

  ushort_t* ws = (ushort_t*)d_ws;
  ushort_t* in1_0 = ws;
  ushort_t* in1_1 = ws + IN1SZ;
  ushort_t* ab = ws + 2 * IN1SZ;
  ushort_t* i2a_0 = ab;
  ushort_t* i2a_1 = ab + IN2ASZ;
  ushort_t* bb = ab + 2 * IN2ASZ;
  ushort_t* i2b_0 = bb;
  ushort_t* i2b_1 = bb + IN2BSZ;
  int* bar = (int*)(ws + BAROFF);
  ushort_t* wp1 = ws + WP1OFF;
  ushort_t* wp2 = ws + WP2OFF;

  // zero state buffers (t=0 h-states + padded borders + barrier slot)
  hipMemsetAsync(ws, 0, (size_t)WP1OFF * 2, stream);
  hipMemsetAsync(out + 768, 0, (size_t)786432 * 4, stream);
  pack_kernel<<<339, 256, 0, stream>>>(w1, w2, fcb, input, pose, wp1, wp2, in1_0);

  persist_kernel<<<NBLOCKS, 256, 0, stream>>>(
      in1_0, in1_1, i2a_0, i2a_1, i2b_0, i2b_1,
      wp1, wp2, b1, b2, c1o, h1o, c2o, h2o,
      fcw, pose, input, bar);
}

// Round 7
// 7221.320 us; speedup vs baseline: 1.3212x; 1.3212x over previous
//
#include <hip/hip_runtime.h>

typedef _Float16 f16;
typedef _Float16 f16x8 __attribute__((ext_vector_type(8)));
typedef float f32x4 __attribute__((ext_vector_type(4)));
typedef unsigned short ushort_t;
typedef unsigned long long u64_t;

// ---------------------------------------------------------------------------
// PoseConvLSTM via implicit-GEMM MFMA.
//
// Round 7: persistent kernel WITHOUT cache-invalidating fences. Round 6's
// counters showed the failure mode: __threadfence_system acquire invalidates
// the whole per-XCD L2 every iteration -> 50 MB/iter refetch (FETCH 6.5 GB,
// 73 us/iter). Only ~1.2 MB/iter actually crosses blocks (h-state), so:
//   - staging-buffer STORES: agent-scope relaxed atomics (2B, write-through)
//   - staging-buffer LOADS:  agent-scope relaxed atomics (8B, L2-bypass,
//     read the device coherence point directly -> no invalidate needed)
//   - barrier: syncthreads -> leader release-fence(agent) (writeback-only)
//     -> per-block flag (512 distinct addrs, no contention) -> block0 polls
//     -> gen broadcast -> compiler-only memory barrier.
// Weights/fcw/bias/c-state stay normal cached accesses and remain L2-hot
// across all 129 iterations (per-XCD working set ~2.2 MB < 4 MB).
//
// Temporal skew kept: per iteration, blocks 0-255 = L1[t], 256-511 = L2[t-1].
// Numerics identical to round 4 (weights split hi/lo, inputs plain f16,
// 2 MFMA per product; absmax 1.56e-2 vs 6.3e-2 threshold).
//
// Buffers (ws, f16 bits), XCD-safe single-writer-role split:
//   in1[parity]:  [66][66][48]  x[t] c0-2, h1prev c3-34, 0 c35-47 (L1-written)
//   in2a[parity]: [66][66][32]  h1[t]   (L1-written only)
//   in2b[parity]: [66][66][64]  h2[t-1] (L2-written only)
//
// d_out (floats): pose[768] | h1[131072] | c1[131072] | h2[262144] | c2[262144]
// ---------------------------------------------------------------------------

#define IN1SZ 209088    // 66*66*48
#define IN2ASZ 139392   // 66*66*32
#define IN2BSZ 278784   // 66*66*64
#define BAROFF 1254528  // ushort offset of barrier block (2*IN1SZ+2*IN2ASZ+2*IN2BSZ)
#define WP1OFF 1258624  // BAROFF + 4096 ushorts (8KB barrier region, memset'd)
#define WP1SZ 147456    // 2mb*18s*4mt*2hl*512
#define WP2OFF (WP1OFF + WP1SZ)
#define WP2SZ 442368    // 2mb*27s*8mt*2hl*512
#define NBLOCKS 512

__device__ __forceinline__ float sigm(float x) {
  return __builtin_amdgcn_rcpf(1.0f + __expf(-x));
}
__device__ __forceinline__ float tanh_fast(float x) {
  float xc = fminf(fmaxf(x, -10.f), 10.f);
  float e = __expf(2.f * xc);
  return (e - 1.f) * __builtin_amdgcn_rcpf(e + 1.f);
}
__device__ __forceinline__ ushort_t f2u(f16 v) { return __builtin_bit_cast(ushort_t, v); }
__device__ __forceinline__ f16x8 u2f(uint4 v) { return __builtin_bit_cast(f16x8, v); }

// agent-scope coherent 2B store (write-through past the XCD L2)
__device__ __forceinline__ void cst2(ushort_t* p, ushort_t v) {
  __hip_atomic_store(p, v, __ATOMIC_RELAXED, __HIP_MEMORY_SCOPE_AGENT);
}
// agent-scope coherent 16B load (2x 8B atomic: bypasses stale L2 lines)
__device__ __forceinline__ uint4 cld16(const ushort_t* p) {
  const u64_t* q = (const u64_t*)p;
  u64_t a = __hip_atomic_load(q, __ATOMIC_RELAXED, __HIP_MEMORY_SCOPE_AGENT);
  u64_t b = __hip_atomic_load(q + 1, __ATOMIC_RELAXED, __HIP_MEMORY_SCOPE_AGENT);
  uint4 r;
  r.x = (unsigned)a; r.y = (unsigned)(a >> 32);
  r.z = (unsigned)b; r.w = (unsigned)(b >> 32);
  return r;
}

// ---- grid barrier: release(writeback-only) + flag array + gen broadcast ----
__device__ __forceinline__ void grid_barrier(int* flags, int* gen, int it) {
  __syncthreads();  // drains each wave's vmcnt: all block stores in L2/L3
  if (threadIdx.x == 0) {
    __builtin_amdgcn_fence(__ATOMIC_RELEASE, "agent");  // wbl2 (no invalidate)
    __hip_atomic_store(&flags[blockIdx.x], it, __ATOMIC_RELAXED,
                       __HIP_MEMORY_SCOPE_AGENT);
  }
  if (blockIdx.x == 0) {
    const int i0 = threadIdx.x, i1 = threadIdx.x + 256;
    for (;;) {
      int a = __hip_atomic_load(&flags[i0], __ATOMIC_RELAXED, __HIP_MEMORY_SCOPE_AGENT);
      int b = __hip_atomic_load(&flags[i1], __ATOMIC_RELAXED, __HIP_MEMORY_SCOPE_AGENT);
      if (__syncthreads_and(a >= it && b >= it)) break;
      __builtin_amdgcn_s_sleep(1);
    }
    if (threadIdx.x == 0)
      __hip_atomic_store(gen, it, __ATOMIC_RELAXED, __HIP_MEMORY_SCOPE_AGENT);
  } else if (threadIdx.x == 0) {
    while (__hip_atomic_load(gen, __ATOMIC_RELAXED, __HIP_MEMORY_SCOPE_AGENT) < it)
      __builtin_amdgcn_s_sleep(1);
  }
  __syncthreads();
  asm volatile("" ::: "memory");  // compiler-only: no hoisting above the spin
}

// ---- init: pack weights (hi/lo) into fragment order, pose=fc_b, stage x[0] ----
__global__ __launch_bounds__(256) void pack_kernel(const float* __restrict__ w1,
                                                   const float* __restrict__ w2,
                                                   const float* __restrict__ fcb,
                                                   const float* __restrict__ x0,
                                                   float* __restrict__ pose,
                                                   ushort_t* __restrict__ wp1,
                                                   ushort_t* __restrict__ wp2,
                                                   ushort_t* __restrict__ in1hi0) {
  int i = blockIdx.x * 256 + threadIdx.x;
  if (i < 55296) {  // wp2: thread per (f, hl, lane), 8 elems each
    int lane = i & 63;
    int r0 = i >> 6;        // [0, 864)
    int hl = r0 & 1;
    int f = r0 >> 1;        // [0, 432) = (mb*27+s)*8+mt
    int mt = f & 7;
    int sm = f >> 3;        // [0,54)
    int s = sm % 27, mb = sm / 27;
    int m = mt * 16 + (lane & 15);
    int rg = mb * 128 + m;
    int h = rg >> 2, G = rg & 3;
    int orow = G * 64 + h;
    int tap = s / 3, cb = (s % 3) * 32;
    int cq = cb + (lane >> 4) * 8;
    for (int j = 0; j < 8; ++j) {
      float v = w2[(orow * 96 + cq + j) * 9 + tap];
      f16 vh = (f16)v;
      f16 vl = (f16)(v - (float)vh);
      wp2[(f * 2 + hl) * 512 + lane * 8 + j] = f2u(hl ? vl : vh);
    }
    return;
  }
  i -= 55296;
  if (i < 18432) {  // wp1
    int lane = i & 63;
    int r0 = i >> 6;        // [0,288)
    int hl = r0 & 1;
    int f = r0 >> 1;        // [0,144) = (mb*18+s)*4+mt
    int mt = f & 3;
    int sm = f >> 2;        // [0,36)
    int s = sm % 18, mb = sm / 18;
    int m = mt * 16 + (lane & 15);
    int rg = mb * 64 + m;
    int h = rg >> 2, G = rg & 3;
    int orow = G * 32 + h;
    int tap = s >> 1, cb = (s & 1) * 32;
    int cq = cb + (lane >> 4) * 8;
    for (int j = 0; j < 8; ++j) {
      int c = cq + j;
      float v = (c < 35) ? w1[(orow * 35 + c) * 9 + tap] : 0.f;
      f16 vh = (f16)v;
      f16 vl = (f16)(v - (float)vh);
      wp1[(f * 2 + hl) * 512 + lane * 8 + j] = f2u(hl ? vl : vh);
    }
    return;
  }
  i -= 18432;
  if (i < 768) { pose[i] = fcb[i % 6]; return; }
  i -= 768;
  if (i < 12288) {  // x[0] -> in1[0] c0-2 (hi only)
    int c = i >> 12, pix = i & 4095;
    int y = pix >> 6, x = pix & 63;
    int pidx = ((y + 1) * 66 + (x + 1)) * 48 + c;
    in1hi0[pidx] = f2u((f16)x0[i]);
  }
}

// ---- one ConvLSTM step for one layer (device body) ----
// bid in [0,256) = 2 M-blocks x 128 pixel tiles (4y x 8x); block 256 = 4 waves.
// L1: input = bhi (in1, 48ch). Writes d1 = in1-next (h1@c3 + x@c0), d2 = in2a.
// L2: input = bhi (in2a, 32ch) + b2hi (in2b, 64ch). Writes d1 = in2b.
template <int LAYER>
__device__ __forceinline__ void conv_body(
    int bid,
    const ushort_t* __restrict__ bhi, const ushort_t* __restrict__ b2hi,
    const ushort_t* __restrict__ wp, const float* __restrict__ bias,
    float* __restrict__ cst, float* __restrict__ hout,              // fp32 c (in-place), h
    ushort_t* __restrict__ d1hi,                                    // primary dest
    ushort_t* __restrict__ d2hi,                                    // secondary (L1 only)
    const float* __restrict__ fcw, float* __restrict__ pose_t,      // L2 only
    const float* __restrict__ xn,                                   // L1 only: x[t+1]
    ushort_t* Bh, float* zs, float (*red)[6]) {
  constexpr int CS = (LAYER == 1) ? 72 : 104;   // LDS c-stride (bank-conflict pad)
  constexpr int NC32 = (LAYER == 1) ? 2 : 3;    // 32-channel chunks
  constexpr int NS = 9 * NC32;                  // k32 steps
  constexpr int MT = (LAYER == 1) ? 4 : 8;      // 16-row m-tiles per block
  constexpr int MTPW = (LAYER == 1) ? 1 : 2;    // m-tiles per wave
  constexpr int H = (LAYER == 1) ? 32 : 64;
  constexpr int ZS = 33;                        // z LDS stride (pad)
  constexpr int D1S = (LAYER == 1) ? 48 : 64;   // primary dest c-stride
  constexpr int D1O = (LAYER == 1) ? 3 : 0;     // primary dest c-offset
  constexpr int DEPTH = 5;                      // A-frag register ring
  constexpr int PRE = DEPTH - 1;

  const int tid = threadIdx.x;
  const int lane = tid & 63;
  const int w = tid >> 6;
  const int mb = bid & 1;
  const int ntile = bid >> 1;
  const int Y0 = (ntile >> 3) * 4;
  const int X0 = (ntile & 7) * 8;

  // ---- A-frag register ring (weight hi+lo): normal cached loads, L2-hot ----
  const ushort_t* aptr[MTPW];
#pragma unroll
  for (int m = 0; m < MTPW; ++m) {
    int f = (mb * NS) * MT + (w * MTPW + m);
    aptr[m] = wp + f * 1024 + lane * 8;
  }
  uint4 A[DEPTH][MTPW][2];
  auto loada = [&](int s) {
#pragma unroll
    for (int m = 0; m < MTPW; ++m) {
      const ushort_t* p = aptr[m] + (size_t)s * (MT * 1024);
      A[s % DEPTH][m][0] = *(const uint4*)(p);
      A[s % DEPTH][m][1] = *(const uint4*)(p + 512);
    }
  };
#pragma unroll
  for (int s = 0; s < PRE; ++s) loada(s);

  // ---- stage halo slab [6y][10x][C] into LDS (coherent agent loads) ----
  if (LAYER == 2) {
    for (int i = tid; i < 720; i += 256) {
      int hy = i / 120, rem = i % 120;
      int hx = rem / 12, c8 = rem % 12;
      int pos = (Y0 + hy) * 66 + X0 + hx;
      int dst = (hy * 10 + hx) * CS + c8 * 8;
      if (c8 < 4) {  // c0-31 from in2a (h1)
        *(uint4*)(&Bh[dst]) = cld16(&bhi[pos * 32 + c8 * 8]);
      } else {       // c32-95 from in2b (h2)
        *(uint4*)(&Bh[dst]) = cld16(&b2hi[pos * 64 + (c8 - 4) * 8]);
      }
    }
  } else {
    for (int i = tid; i < 360; i += 256) {
      int hy = i / 60, rem = i % 60;
      int hx = rem / 6, c8 = (rem % 6) * 8;
      int src = ((Y0 + hy) * 66 + X0 + hx) * 48 + c8;
      int dst = (hy * 10 + hx) * CS + c8;
      *(uint4*)(&Bh[dst]) = cld16(&bhi[src]);
    }
    for (int i = tid; i < 120; i += 256) {  // zero-pad c 48..63 (read by frags)
      int hp = i >> 1;
      int dst = hp * CS + 48 + (i & 1) * 8;
      *(uint4*)(&Bh[dst]) = uint4{0, 0, 0, 0};
    }
  }
  __syncthreads();

  // ---- K-loop: A frags from registers (ring-prefetched), B frags from LDS ----
  const int n = lane & 15;
  const int q = lane >> 4;
  const int py = n >> 3, px = n & 7;

  f32x4 acc[MTPW][2];
#pragma unroll
  for (int m = 0; m < MTPW; ++m)
#pragma unroll
    for (int nt = 0; nt < 2; ++nt) acc[m][nt] = f32x4{0.f, 0.f, 0.f, 0.f};

#pragma unroll
  for (int s = 0; s < NS; ++s) {
    // rolling prefetch: writes ring slot consumed LAST iteration (WAR-bounded)
    if (s + PRE < NS) loada(s + PRE);
    const int tap = s / NC32, cc = s % NC32;
    const int ty = tap / 3, tx = tap % 3;
    const int coff = cc * 32 + q * 8;
    f16x8 bfh[2];
#pragma unroll
    for (int nt = 0; nt < 2; ++nt) {
      int hp = (py + nt * 2 + ty) * 10 + (px + tx);
      bfh[nt] = u2f(*(const uint4*)(&Bh[hp * CS + coff]));
    }
#pragma unroll
    for (int m = 0; m < MTPW; ++m) {
      f16x8 ah = u2f(A[s % DEPTH][m][0]);
      f16x8 al = u2f(A[s % DEPTH][m][1]);
#pragma unroll
      for (int nt = 0; nt < 2; ++nt) {
        acc[m][nt] = __builtin_amdgcn_mfma_f32_16x16x32_f16(ah, bfh[nt], acc[m][nt], 0, 0, 0);
        acc[m][nt] = __builtin_amdgcn_mfma_f32_16x16x32_f16(al, bfh[nt], acc[m][nt], 0, 0, 0);
      }
    }
  }

  // ---- z exchange through LDS ----
  __syncthreads();
#pragma unroll
  for (int m = 0; m < MTPW; ++m) {
    int mt = w * MTPW + m;
#pragma unroll
    for (int nt = 0; nt < 2; ++nt)
#pragma unroll
      for (int i = 0; i < 4; ++i) zs[(mt * 16 + q * 4 + i) * ZS + nt * 16 + n] = acc[m][nt][i];
  }
  __syncthreads();

  // ---- LSTM cell + state writes (+ FC fuse for L2) ----
  constexpr int NCELL = (MT * 4 * 32) / 256;  // cells per thread (L2: 4, L1: 2)
  float p6[6] = {0, 0, 0, 0, 0, 0};
#pragma unroll
  for (int i = 0; i < NCELL; ++i) {
    int idx = i * 256 + tid;
    int ch = idx >> 5, pI = idx & 31;
    float zi = zs[(ch * 4 + 0) * ZS + pI];
    float zf = zs[(ch * 4 + 1) * ZS + pI];
    float zo = zs[(ch * 4 + 2) * ZS + pI];
    float zg = zs[(ch * 4 + 3) * ZS + pI];
    int hg = mb * (MT * 4) + ch;
    zi += bias[0 * H + hg];
    zf += bias[1 * H + hg];
    zo += bias[2 * H + hg];
    zg += bias[3 * H + hg];
    int y = Y0 + (pI >> 3), x = X0 + (pI & 7);
    int cidx = hg * 4096 + y * 64 + x;
    float cold = cst[cidx];
    float cn = sigm(zf) * cold + sigm(zi) * tanh_fast(zg);
    float hn = sigm(zo) * tanh_fast(cn);
    cst[cidx] = cn;
    hout[cidx] = hn;
    f16 hh = (f16)hn;
    int pidx = (y + 1) * 66 + (x + 1);
    cst2(&d1hi[pidx * D1S + D1O + hg], f2u(hh));
    if (LAYER == 1) {
      cst2(&d2hi[pidx * 32 + hg], f2u(hh));   // in2a: h1, 32-ch stride
    } else {
#pragma unroll
      for (int j = 0; j < 6; ++j) p6[j] += hn * fcw[j * 262144 + cidx];
    }
  }

  if (LAYER == 2) {
#pragma unroll
    for (int j = 0; j < 6; ++j)
#pragma unroll
      for (int off = 32; off > 0; off >>= 1) p6[j] += __shfl_xor(p6[j], off, 64);
    if (lane == 0)
#pragma unroll
      for (int j = 0; j < 6; ++j) red[w][j] = p6[j];
    __syncthreads();
    if (tid < 6) atomicAdd(pose_t + tid, red[0][tid] + red[1][tid] + red[2][tid] + red[3][tid]);
  } else {
    // stage x[t+1] into in1 next-parity (c0-2); d1 is in1-next
    if (mb == 0 && tid < 32) {
      int y = Y0 + (tid >> 3), x = X0 + (tid & 7);
      int pidx = (y + 1) * 66 + (x + 1);
#pragma unroll
      for (int c = 0; c < 3; ++c) {
        cst2(&d1hi[pidx * 48 + c], f2u((f16)xn[c * 4096 + y * 64 + x]));
      }
    }
  }
}

// ---- persistent kernel: t-loop inside, flag-array grid barrier per step ----
// blocks 0-255 = L1[t], 256-511 = L2[t-1]; 512 blocks = 2/CU exactly.
__global__ __launch_bounds__(256, 2) void persist_kernel(
    ushort_t* __restrict__ in1_0, ushort_t* __restrict__ in1_1,
    ushort_t* __restrict__ i2a_0, ushort_t* __restrict__ i2a_1,
    ushort_t* __restrict__ i2b_0, ushort_t* __restrict__ i2b_1,
    const ushort_t* __restrict__ wp1, const ushort_t* __restrict__ wp2,
    const float* __restrict__ b1, const float* __restrict__ b2,
    float* __restrict__ c1o, float* __restrict__ h1o,
    float* __restrict__ c2o, float* __restrict__ h2o,
    const float* __restrict__ fcw, float* __restrict__ pose,
    const float* __restrict__ input, int* __restrict__ bar) {
  // union'd shared memory: max over both roles (L2 sizes), ~29.5 KB -> 2/CU
  __shared__ __align__(16) ushort_t Bh[6240];   // max(60*72, 60*104)
  __shared__ float zs[4224];                    // max(64,128)*33
  __shared__ float red[4][6];

  const int bid = blockIdx.x;
  int* flags = bar;        // 512 ints, zeroed by host memset each call
  int* gen = bar + 544;    // own 128B line
  ushort_t* in1[2] = {in1_0, in1_1};
  ushort_t* i2a[2] = {i2a_0, i2a_1};
  ushort_t* i2b[2] = {i2b_0, i2b_1};

  for (int t = 0; t <= 128; ++t) {
    const int p = t & 1, pn = p ^ 1;
    if (bid < 256) {
      if (t < 128) {
        int tn = (t + 1 < 128) ? t + 1 : 127;
        conv_body<1>(bid, in1[p], nullptr, wp1, b1, c1o, h1o,
                     in1[pn],               // h1 -> in1 next @c3 (+ x[t+1] @c0-2)
                     i2a[p],                // h1 -> in2a[t&1]
                     nullptr, nullptr,
                     input + (size_t)tn * 12288, Bh, zs, red);
      }
    } else {
      if (t >= 1) {
        conv_body<2>(bid - 256, i2a[pn], i2b[pn], wp2, b2, c2o, h2o,
                     i2b[p],                // h2 -> in2b[t&1]
                     nullptr,
                     fcw, pose + (t - 1) * 6, nullptr, Bh, zs, red);
      }
    }
    grid_barrier(flags, gen, t + 1);
  }
}

extern "C" void kernel_launch(void* const* d_in, const int* in_sizes, int n_in, void* d_out,
                              int out_size, void* d_ws, size_t ws_size, hipStream_t stream) {
  const float* input = (const float*)d_in[0];
  const float* w1 = (const float*)d_in[1];
  const float* b1 = (const float*)d_in[2];
  const float* w2 = (const float*)d_in[3];
  const float* b2 = (const float*)d_in[4];
  const float* fcw = (const float*)d_in[5];
  const float* fcb = (const float*)d_in[6];

  float* out = (float*)d_out;
  float* pose = out;
  float* h1o = out + 768;
  float* c1o = h1o + 131072;
  float* h2o = c1o + 131072;
  float* c2o = h2o + 262144;

  ushort_t* ws = (ushort_t*)d_ws;
  ushort_t* in1_0 = ws;
  ushort_t* in1_1 = ws + IN1SZ;
  ushort_t* ab = ws + 2 * IN1SZ;
  ushort_t* i2a_0 = ab;
  ushort_t* i2a_1 = ab + IN2ASZ;
  ushort_t* bb = ab + 2 * IN2ASZ;
  ushort_t* i2b_0 = bb;
  ushort_t* i2b_1 = bb + IN2BSZ;
  int* bar = (int*)(ws + BAROFF);
  ushort_t* wp1 = ws + WP1OFF;
  ushort_t* wp2 = ws + WP2OFF;

  // zero state buffers (t=0 h-states + padded borders + barrier region)
  hipMemsetAsync(ws, 0, (size_t)WP1OFF * 2, stream);
  hipMemsetAsync(out + 768, 0, (size_t)786432 * 4, stream);
  pack_kernel<<<339, 256, 0, stream>>>(w1, w2, fcb, input, pose, wp1, wp2, in1_0);

  persist_kernel<<<NBLOCKS, 256, 0, stream>>>(
      in1_0, in1_1, i2a_0, i2a_1, i2b_0, i2b_1,
      wp1, wp2, b1, b2, c1o, h1o, c2o, h2o,
      fcw, pose, input, bar);
}

// Round 8
// 6616.923 us; speedup vs baseline: 1.4419x; 1.0913x over previous
//
#include <hip/hip_runtime.h>

typedef _Float16 f16;
typedef _Float16 f16x8 __attribute__((ext_vector_type(8)));
typedef float f32x4 __attribute__((ext_vector_type(4)));
typedef unsigned short ushort_t;
typedef unsigned long long u64_t;

// ---------------------------------------------------------------------------
// PoseConvLSTM via implicit-GEMM MFMA. Persistent kernel + grid barrier.
//
// Round 8: kill the 50 MB/iter beyond-L2 traffic (FETCH identical in r6/r7 =>
// structural, not fence-induced; 50MB @ ~1.2TB/s ~= the whole 55us/iter):
//  1) fcw repacked at init to fcwp[cidx*6+j] (f32, contiguous 24B/cell).
//     Old j*262144+cidx layout used 32B per 128B line on a full 6.29MB sweep
//     every iteration (~25 MB/iter overfetch).
//  2) h-staging stores: LDS-transpose then 8B agent atomics (32-64B
//     contiguous per pixel). Old per-cell 2B stores hit 64 lines/wave ->
//     ~16x write amplification (observed WRITE 12.9 MB/iter vs ~4 expected).
//     To make in1 h-stores 8B-aligned, x moves to channels 32-34 (weights
//     re-permuted at pack time to match; c0-31 = h1).
//  3) all concurrent writers still own disjoint 32B granules (r2 lesson).
//
// Buffers (ws, f16 bits), XCD-safe single-writer-role split:
//   in1[parity]:  [66][66][48]  h1prev c0-31, x[t] c32-34, 0 c35-47 (L1-written)
//   in2a[parity]: [66][66][32]  h1[t]   (L1-written only)
//   in2b[parity]: [66][66][64]  h2[t-1] (L2-written only)
//
// d_out (floats): pose[768] | h1[131072] | c1[131072] | h2[262144] | c2[262144]
// ---------------------------------------------------------------------------

#define IN1SZ 209088    // 66*66*48
#define IN2ASZ 139392   // 66*66*32
#define IN2BSZ 278784   // 66*66*64
#define BAROFF 1254528  // ushort offset of barrier block (2*IN1SZ+2*IN2ASZ+2*IN2BSZ)
#define WP1OFF 1258624  // BAROFF + 4096 ushorts (8KB barrier region, memset'd)
#define WP1SZ 147456    // 2mb*18s*4mt*2hl*512
#define WP2OFF (WP1OFF + WP1SZ)
#define WP2SZ 442368    // 2mb*27s*8mt*2hl*512
#define FCWPOFF (WP2OFF + WP2SZ)  // 1848448 ushorts -> float* (4B aligned)
#define NBLOCKS 512

__device__ __forceinline__ float sigm(float x) {
  return __builtin_amdgcn_rcpf(1.0f + __expf(-x));
}
__device__ __forceinline__ float tanh_fast(float x) {
  float xc = fminf(fmaxf(x, -10.f), 10.f);
  float e = __expf(2.f * xc);
  return (e - 1.f) * __builtin_amdgcn_rcpf(e + 1.f);
}
__device__ __forceinline__ ushort_t f2u(f16 v) { return __builtin_bit_cast(ushort_t, v); }
__device__ __forceinline__ f16x8 u2f(uint4 v) { return __builtin_bit_cast(f16x8, v); }

// agent-scope coherent 2B store (write-through past the XCD L2)
__device__ __forceinline__ void cst2(ushort_t* p, ushort_t v) {
  __hip_atomic_store(p, v, __ATOMIC_RELAXED, __HIP_MEMORY_SCOPE_AGENT);
}
// agent-scope coherent 8B store
__device__ __forceinline__ void cst8(ushort_t* p, u64_t v) {
  __hip_atomic_store((u64_t*)p, v, __ATOMIC_RELAXED, __HIP_MEMORY_SCOPE_AGENT);
}
// agent-scope coherent 16B load (2x 8B atomic: bypasses stale L2 lines)
__device__ __forceinline__ uint4 cld16(const ushort_t* p) {
  const u64_t* q = (const u64_t*)p;
  u64_t a = __hip_atomic_load(q, __ATOMIC_RELAXED, __HIP_MEMORY_SCOPE_AGENT);
  u64_t b = __hip_atomic_load(q + 1, __ATOMIC_RELAXED, __HIP_MEMORY_SCOPE_AGENT);
  uint4 r;
  r.x = (unsigned)a; r.y = (unsigned)(a >> 32);
  r.z = (unsigned)b; r.w = (unsigned)(b >> 32);
  return r;
}

// ---- grid barrier: release(writeback-only) + flag array + gen broadcast ----
__device__ __forceinline__ void grid_barrier(int* flags, int* gen, int it) {
  __syncthreads();  // drains each wave's vmcnt: all block stores issued
  if (threadIdx.x == 0) {
    __builtin_amdgcn_fence(__ATOMIC_RELEASE, "agent");  // wbl2 (no invalidate)
    __hip_atomic_store(&flags[blockIdx.x], it, __ATOMIC_RELAXED,
                       __HIP_MEMORY_SCOPE_AGENT);
  }
  if (blockIdx.x == 0) {
    const int i0 = threadIdx.x, i1 = threadIdx.x + 256;
    for (;;) {
      int a = __hip_atomic_load(&flags[i0], __ATOMIC_RELAXED, __HIP_MEMORY_SCOPE_AGENT);
      int b = __hip_atomic_load(&flags[i1], __ATOMIC_RELAXED, __HIP_MEMORY_SCOPE_AGENT);
      if (__syncthreads_and(a >= it && b >= it)) break;
      __builtin_amdgcn_s_sleep(1);
    }
    if (threadIdx.x == 0)
      __hip_atomic_store(gen, it, __ATOMIC_RELAXED, __HIP_MEMORY_SCOPE_AGENT);
  } else if (threadIdx.x == 0) {
    while (__hip_atomic_load(gen, __ATOMIC_RELAXED, __HIP_MEMORY_SCOPE_AGENT) < it)
      __builtin_amdgcn_s_sleep(1);
  }
  __syncthreads();
  asm volatile("" ::: "memory");  // compiler-only: no hoisting above the spin
}

// ---- init: pack weights (hi/lo, x@c32-34 order), fcw transpose, x[0] ----
__global__ __launch_bounds__(256) void pack_kernel(const float* __restrict__ w1,
                                                   const float* __restrict__ w2,
                                                   const float* __restrict__ fcb,
                                                   const float* __restrict__ x0,
                                                   const float* __restrict__ fcw,
                                                   float* __restrict__ pose,
                                                   ushort_t* __restrict__ wp1,
                                                   ushort_t* __restrict__ wp2,
                                                   ushort_t* __restrict__ in1hi0,
                                                   float* __restrict__ fcwp) {
  int i = blockIdx.x * 256 + threadIdx.x;
  if (i < 55296) {  // wp2: thread per (f, hl, lane), 8 elems each
    int lane = i & 63;
    int r0 = i >> 6;        // [0, 864)
    int hl = r0 & 1;
    int f = r0 >> 1;        // [0, 432) = (mb*27+s)*8+mt
    int mt = f & 7;
    int sm = f >> 3;        // [0,54)
    int s = sm % 27, mb = sm / 27;
    int m = mt * 16 + (lane & 15);
    int rg = mb * 128 + m;
    int h = rg >> 2, G = rg & 3;
    int orow = G * 64 + h;
    int tap = s / 3, cb = (s % 3) * 32;
    int cq = cb + (lane >> 4) * 8;
    for (int j = 0; j < 8; ++j) {
      float v = w2[(orow * 96 + cq + j) * 9 + tap];
      f16 vh = (f16)v;
      f16 vl = (f16)(v - (float)vh);
      wp2[(f * 2 + hl) * 512 + lane * 8 + j] = f2u(hl ? vl : vh);
    }
    return;
  }
  i -= 55296;
  if (i < 18432) {  // wp1 (channel order: c0-31 = h1 (ref 3+c), c32-34 = x)
    int lane = i & 63;
    int r0 = i >> 6;        // [0,288)
    int hl = r0 & 1;
    int f = r0 >> 1;        // [0,144) = (mb*18+s)*4+mt
    int mt = f & 3;
    int sm = f >> 2;        // [0,36)
    int s = sm % 18, mb = sm / 18;
    int m = mt * 16 + (lane & 15);
    int rg = mb * 64 + m;
    int h = rg >> 2, G = rg & 3;
    int orow = G * 32 + h;
    int tap = s >> 1, cb = (s & 1) * 32;
    int cq = cb + (lane >> 4) * 8;
    for (int j = 0; j < 8; ++j) {
      int c = cq + j;
      float v = 0.f;
      if (c < 32) v = w1[(orow * 35 + c + 3) * 9 + tap];
      else if (c < 35) v = w1[(orow * 35 + c - 32) * 9 + tap];
      f16 vh = (f16)v;
      f16 vl = (f16)(v - (float)vh);
      wp1[(f * 2 + hl) * 512 + lane * 8 + j] = f2u(hl ? vl : vh);
    }
    return;
  }
  i -= 18432;
  if (i < 768) { pose[i] = fcb[i % 6]; return; }
  i -= 768;
  if (i < 12288) {  // x[0] -> in1[0] c32-34
    int c = i >> 12, pix = i & 4095;
    int y = pix >> 6, x = pix & 63;
    int pidx = ((y + 1) * 66 + (x + 1)) * 48 + 32 + c;
    in1hi0[pidx] = f2u((f16)x0[i]);
    return;
  }
  i -= 12288;
  if (i < 262144) {  // fcw transpose: fcwp[cidx*6+j] = fcw[j*262144+cidx]
    float* dst = fcwp + (size_t)i * 6;
#pragma unroll
    for (int j = 0; j < 6; ++j) dst[j] = fcw[(size_t)j * 262144 + i];
  }
}

// ---- one ConvLSTM step for one layer (device body) ----
// bid in [0,256) = 2 M-blocks x 128 pixel tiles (4y x 8x); block 256 = 4 waves.
// L1: input = bhi (in1, 48ch: h1@c0-31, x@c32-34). Writes d1 = in1-next (h1),
//     d2 = in2a. L2: input = bhi (in2a) + b2hi (in2b). Writes d1 = in2b.
template <int LAYER>
__device__ __forceinline__ void conv_body(
    int bid,
    const ushort_t* __restrict__ bhi, const ushort_t* __restrict__ b2hi,
    const ushort_t* __restrict__ wp, const float* __restrict__ bias,
    float* __restrict__ cst, float* __restrict__ hout,              // fp32 c (in-place), h
    ushort_t* __restrict__ d1hi,                                    // primary dest
    ushort_t* __restrict__ d2hi,                                    // secondary (L1 only)
    const float* __restrict__ fcwp, float* __restrict__ pose_t,     // L2 only
    const float* __restrict__ xn,                                   // L1 only: x[t+1]
    ushort_t* Bh, float* zs, ushort_t* hs, float (*red)[6]) {
  constexpr int CS = (LAYER == 1) ? 72 : 104;   // LDS c-stride (bank-conflict pad)
  constexpr int NC32 = (LAYER == 1) ? 2 : 3;    // 32-channel chunks
  constexpr int NS = 9 * NC32;                  // k32 steps
  constexpr int MT = (LAYER == 1) ? 4 : 8;      // 16-row m-tiles per block
  constexpr int MTPW = (LAYER == 1) ? 1 : 2;    // m-tiles per wave
  constexpr int H = (LAYER == 1) ? 32 : 64;
  constexpr int ZS = 33;                        // z LDS stride (pad)
  constexpr int DEPTH = 5;                      // A-frag register ring
  constexpr int PRE = DEPTH - 1;

  const int tid = threadIdx.x;
  const int lane = tid & 63;
  const int w = tid >> 6;
  const int mb = bid & 1;
  const int ntile = bid >> 1;
  const int Y0 = (ntile >> 3) * 4;
  const int X0 = (ntile & 7) * 8;

  // ---- A-frag register ring (weight hi+lo): normal cached loads, L2-hot ----
  const ushort_t* aptr[MTPW];
#pragma unroll
  for (int m = 0; m < MTPW; ++m) {
    int f = (mb * NS) * MT + (w * MTPW + m);
    aptr[m] = wp + f * 1024 + lane * 8;
  }
  uint4 A[DEPTH][MTPW][2];
  auto loada = [&](int s) {
#pragma unroll
    for (int m = 0; m < MTPW; ++m) {
      const ushort_t* p = aptr[m] + (size_t)s * (MT * 1024);
      A[s % DEPTH][m][0] = *(const uint4*)(p);
      A[s % DEPTH][m][1] = *(const uint4*)(p + 512);
    }
  };
#pragma unroll
  for (int s = 0; s < PRE; ++s) loada(s);

  // ---- stage halo slab [6y][10x][C] into LDS (coherent agent loads) ----
  if (LAYER == 2) {
    for (int i = tid; i < 720; i += 256) {
      int hy = i / 120, rem = i % 120;
      int hx = rem / 12, c8 = rem % 12;
      int pos = (Y0 + hy) * 66 + X0 + hx;
      int dst = (hy * 10 + hx) * CS + c8 * 8;
      if (c8 < 4) {  // c0-31 from in2a (h1)
        *(uint4*)(&Bh[dst]) = cld16(&bhi[pos * 32 + c8 * 8]);
      } else {       // c32-95 from in2b (h2)
        *(uint4*)(&Bh[dst]) = cld16(&b2hi[pos * 64 + (c8 - 4) * 8]);
      }
    }
  } else {
    for (int i = tid; i < 360; i += 256) {
      int hy = i / 60, rem = i % 60;
      int hx = rem / 6, c8 = (rem % 6) * 8;
      int src = ((Y0 + hy) * 66 + X0 + hx) * 48 + c8;
      int dst = (hy * 10 + hx) * CS + c8;
      *(uint4*)(&Bh[dst]) = cld16(&bhi[src]);
    }
    for (int i = tid; i < 120; i += 256) {  // zero-pad c 48..63 (read by frags)
      int hp = i >> 1;
      int dst = hp * CS + 48 + (i & 1) * 8;
      *(uint4*)(&Bh[dst]) = uint4{0, 0, 0, 0};
    }
  }
  __syncthreads();

  // ---- K-loop: A frags from registers (ring-prefetched), B frags from LDS ----
  const int n = lane & 15;
  const int q = lane >> 4;
  const int py = n >> 3, px = n & 7;

  f32x4 acc[MTPW][2];
#pragma unroll
  for (int m = 0; m < MTPW; ++m)
#pragma unroll
    for (int nt = 0; nt < 2; ++nt) acc[m][nt] = f32x4{0.f, 0.f, 0.f, 0.f};

#pragma unroll
  for (int s = 0; s < NS; ++s) {
    // rolling prefetch: writes ring slot consumed LAST iteration (WAR-bounded)
    if (s + PRE < NS) loada(s + PRE);
    const int tap = s / NC32, cc = s % NC32;
    const int ty = tap / 3, tx = tap % 3;
    const int coff = cc * 32 + q * 8;
    f16x8 bfh[2];
#pragma unroll
    for (int nt = 0; nt < 2; ++nt) {
      int hp = (py + nt * 2 + ty) * 10 + (px + tx);
      bfh[nt] = u2f(*(const uint4*)(&Bh[hp * CS + coff]));
    }
#pragma unroll
    for (int m = 0; m < MTPW; ++m) {
      f16x8 ah = u2f(A[s % DEPTH][m][0]);
      f16x8 al = u2f(A[s % DEPTH][m][1]);
#pragma unroll
      for (int nt = 0; nt < 2; ++nt) {
        acc[m][nt] = __builtin_amdgcn_mfma_f32_16x16x32_f16(ah, bfh[nt], acc[m][nt], 0, 0, 0);
        acc[m][nt] = __builtin_amdgcn_mfma_f32_16x16x32_f16(al, bfh[nt], acc[m][nt], 0, 0, 0);
      }
    }
  }

  // ---- z exchange through LDS ----
  __syncthreads();
#pragma unroll
  for (int m = 0; m < MTPW; ++m) {
    int mt = w * MTPW + m;
#pragma unroll
    for (int nt = 0; nt < 2; ++nt)
#pragma unroll
      for (int i = 0; i < 4; ++i) zs[(mt * 16 + q * 4 + i) * ZS + nt * 16 + n] = acc[m][nt][i];
  }
  __syncthreads();

  // ---- LSTM cell + f32 state writes; hh staged into LDS (+ FC fuse L2) ----
  constexpr int NCELL = (MT * 4 * 32) / 256;  // cells per thread (L2: 4, L1: 2)
  float p6[6] = {0, 0, 0, 0, 0, 0};
#pragma unroll
  for (int i = 0; i < NCELL; ++i) {
    int idx = i * 256 + tid;
    int ch = idx >> 5, pI = idx & 31;
    float zi = zs[(ch * 4 + 0) * ZS + pI];
    float zf = zs[(ch * 4 + 1) * ZS + pI];
    float zo = zs[(ch * 4 + 2) * ZS + pI];
    float zg = zs[(ch * 4 + 3) * ZS + pI];
    int hg = mb * (MT * 4) + ch;
    zi += bias[0 * H + hg];
    zf += bias[1 * H + hg];
    zo += bias[2 * H + hg];
    zg += bias[3 * H + hg];
    int y = Y0 + (pI >> 3), x = X0 + (pI & 7);
    int cidx = hg * 4096 + y * 64 + x;
    float cold = cst[cidx];
    float cn = sigm(zf) * cold + sigm(zi) * tanh_fast(zg);
    float hn = sigm(zo) * tanh_fast(cn);
    cst[cidx] = cn;
    hout[cidx] = hn;
    hs[pI * 36 + ch] = f2u((f16)hn);
    if (LAYER == 2) {
#pragma unroll
      for (int j = 0; j < 6; ++j) p6[j] += hn * fcwp[(size_t)cidx * 6 + j];
    }
  }
  __syncthreads();  // hs complete

  // ---- coalesced h-staging stores (8B agent atomics, full granules) ----
  if (LAYER == 2) {
    int pxi = tid & 31, g = tid >> 5;   // 32 px x 8 ch-groups of 4
    int y = Y0 + (pxi >> 3), x = X0 + (pxi & 7);
    int pidx = (y + 1) * 66 + (x + 1);
    u64_t v = *(const u64_t*)&hs[pxi * 36 + g * 4];
    cst8(&d1hi[pidx * 64 + mb * 32 + g * 4], v);   // in2b: h2
  } else {
    int t2 = tid & 127;
    int pxi = t2 & 31, g = t2 >> 5;     // 32 px x 4 ch-groups of 4
    int y = Y0 + (pxi >> 3), x = X0 + (pxi & 7);
    int pidx = (y + 1) * 66 + (x + 1);
    u64_t v = *(const u64_t*)&hs[pxi * 36 + g * 4];
    if (tid < 128) {
      cst8(&d2hi[pidx * 32 + mb * 16 + g * 4], v); // in2a: h1
    } else {
      cst8(&d1hi[pidx * 48 + mb * 16 + g * 4], v); // in1-next: h1 @c0
    }
    // stage x[t+1] into in1 next-parity (c32-34)
    if (mb == 0 && tid < 32) {
      int yy = Y0 + (tid >> 3), xx = X0 + (tid & 7);
      int pidx2 = (yy + 1) * 66 + (xx + 1);
#pragma unroll
      for (int c = 0; c < 3; ++c) {
        cst2(&d1hi[pidx2 * 48 + 32 + c], f2u((f16)xn[c * 4096 + yy * 64 + xx]));
      }
    }
  }

  if (LAYER == 2) {
#pragma unroll
    for (int j = 0; j < 6; ++j)
#pragma unroll
      for (int off = 32; off > 0; off >>= 1) p6[j] += __shfl_xor(p6[j], off, 64);
    if (lane == 0)
#pragma unroll
      for (int j = 0; j < 6; ++j) red[w][j] = p6[j];
    __syncthreads();
    if (tid < 6) atomicAdd(pose_t + tid, red[0][tid] + red[1][tid] + red[2][tid] + red[3][tid]);
  }
}

// ---- persistent kernel: t-loop inside, flag-array grid barrier per step ----
// blocks 0-255 = L1[t], 256-511 = L2[t-1]; 512 blocks = 2/CU exactly.
__global__ __launch_bounds__(256, 2) void persist_kernel(
    ushort_t* __restrict__ in1_0, ushort_t* __restrict__ in1_1,
    ushort_t* __restrict__ i2a_0, ushort_t* __restrict__ i2a_1,
    ushort_t* __restrict__ i2b_0, ushort_t* __restrict__ i2b_1,
    const ushort_t* __restrict__ wp1, const ushort_t* __restrict__ wp2,
    const float* __restrict__ b1, const float* __restrict__ b2,
    float* __restrict__ c1o, float* __restrict__ h1o,
    float* __restrict__ c2o, float* __restrict__ h2o,
    const float* __restrict__ fcwp, float* __restrict__ pose,
    const float* __restrict__ input, int* __restrict__ bar) {
  __shared__ __align__(16) ushort_t Bh[6240];   // max(60*72, 60*104)
  __shared__ float zs[4224];                    // max(64,128)*33
  __shared__ __align__(8) ushort_t hs[1152];    // 32px * 36-stride hh stage
  __shared__ float red[4][6];

  const int bid = blockIdx.x;
  int* flags = bar;        // 512 ints, zeroed by host memset each call
  int* gen = bar + 544;    // own 128B line
  ushort_t* in1[2] = {in1_0, in1_1};
  ushort_t* i2a[2] = {i2a_0, i2a_1};
  ushort_t* i2b[2] = {i2b_0, i2b_1};

  for (int t = 0; t <= 128; ++t) {
    const int p = t & 1, pn = p ^ 1;
    if (bid < 256) {
      if (t < 128) {
        int tn = (t + 1 < 128) ? t + 1 : 127;
        conv_body<1>(bid, in1[p], nullptr, wp1, b1, c1o, h1o,
                     in1[pn],               // h1 -> in1 next @c0 (+ x[t+1] @c32)
                     i2a[p],                // h1 -> in2a[t&1]
                     nullptr, nullptr,
                     input + (size_t)tn * 12288, Bh, zs, hs, red);
      }
    } else {
      if (t >= 1) {
        conv_body<2>(bid - 256, i2a[pn], i2b[pn], wp2, b2, c2o, h2o,
                     i2b[p],                // h2 -> in2b[t&1]
                     nullptr,
                     fcwp, pose + (t - 1) * 6, nullptr, Bh, zs, hs, red);
      }
    }
    grid_barrier(flags, gen, t + 1);
  }
}

extern "C" void kernel_launch(void* const* d_in, const int* in_sizes, int n_in, void* d_out,
                              int out_size, void* d_ws, size_t ws_size, hipStream_t stream) {
  const float* input = (const float*)d_in[0];
  const float* w1 = (const float*)d_in[1];
  const float* b1 = (const float*)d_in[2];
  const float* w2 = (const float*)d_in[3];
  const float* b2 = (const float*)d_in[4];
  const float* fcw = (const float*)d_in[5];
  const float* fcb = (const float*)d_in[6];

  float* out = (float*)d_out;
  float* pose = out;
  float* h1o = out + 768;
  float* c1o = h1o + 131072;
  float* h2o = c1o + 131072;
  float* c2o = h2o + 262144;

  ushort_t* ws = (ushort_t*)d_ws;
  ushort_t* in1_0 = ws;
  ushort_t* in1_1 = ws + IN1SZ;
  ushort_t* ab = ws + 2 * IN1SZ;
  ushort_t* i2a_0 = ab;
  ushort_t* i2a_1 = ab + IN2ASZ;
  ushort_t* bb = ab + 2 * IN2ASZ;
  ushort_t* i2b_0 = bb;
  ushort_t* i2b_1 = bb + IN2BSZ;
  int* bar = (int*)(ws + BAROFF);
  ushort_t* wp1 = ws + WP1OFF;
  ushort_t* wp2 = ws + WP2OFF;
  float* fcwp = (float*)(ws + FCWPOFF);  // 6.29 MB

  // zero state buffers (t=0 h-states + padded borders + barrier region)
  hipMemsetAsync(ws, 0, (size_t)WP1OFF * 2, stream);
  hipMemsetAsync(out + 768, 0, (size_t)786432 * 4, stream);
  pack_kernel<<<1363, 256, 0, stream>>>(w1, w2, fcb, input, fcw, pose, wp1, wp2,
                                        in1_0, fcwp);

  persist_kernel<<<NBLOCKS, 256, 0, stream>>>(
      in1_0, in1_1, i2a_0, i2a_1, i2b_0, i2b_1,
      wp1, wp2, b1, b2, c1o, h1o, c2o, h2o,
      fcwp, pose, input, bar);
}

// Round 9
// 2294.733 us; speedup vs baseline: 4.1577x; 2.8835x over previous
//
#include <hip/hip_runtime.h>

typedef _Float16 f16;
typedef _Float16 f16x8 __attribute__((ext_vector_type(8)));
typedef float f32x4 __attribute__((ext_vector_type(4)));
typedef unsigned short ushort_t;
typedef unsigned long long u64_t;

// ---------------------------------------------------------------------------
// PoseConvLSTM via implicit-GEMM MFMA. Multi-launch temporal-skew fusion.
//
// Round 9: REVERT to the round-4 multi-launch structure (3611 us, passed;
// persistent-kernel rounds 6-8 were all slower -- software coherence via
// uncoalesced agent atomics costs more than kernel-boundary coherence).
// Port the two traffic fixes that round 8 validated:
//  1) fcwp transpose-pack: fcwp[cidx*6+j] f32 (24B contiguous per cell).
//     Old fcw[j*262144+cidx] used 32B per 128B line over a 6.29MB sweep
//     every step (~25 MB/step overfetch).
//  2) coalesced h-staging stores: LDS-transpose then plain 8B stores
//     (uint2), full 32B granules per wave. Old per-cell 2B stores hit 64
//     lines/wave (~16x write amplification). h1 moves to c0-31 of in1,
//     x[t] to c32-34 (wp1 re-permuted at pack time to match).
// All stores are NORMAL stores: kernel boundaries give cross-XCD coherence.
// Concurrent writers within one dispatch own disjoint 32B granules (r2/r3).
//
// Kernel K_t: blocks 0-255 = L1[t], blocks 256-511 = L2[t-1] (temporal skew,
// no intra-kernel dependency).
//   in1[parity]:  [66][66][48]  h1prev c0-31, x[t] c32-34, 0 c35-47 (L1-writ)
//   in2a[parity]: [66][66][32]  h1[t]   (L1-written only)
//   in2b[parity]: [66][66][64]  h2[t-1] (L2-written only)
//
// d_out (floats): pose[768] | h1[131072] | c1[131072] | h2[262144] | c2[262144]
// ---------------------------------------------------------------------------

#define IN1SZ 209088    // 66*66*48
#define IN2ASZ 139392   // 66*66*32
#define IN2BSZ 278784   // 66*66*64
#define WP1OFF 1254528  // ushort offset of wp1 (2*IN1SZ + 2*IN2ASZ + 2*IN2BSZ)
#define WP1SZ 147456    // 2mb*18s*4mt*2hl*512
#define WP2OFF (WP1OFF + WP1SZ)
#define WP2SZ 442368    // 2mb*27s*8mt*2hl*512
#define FCWPOFF (WP2OFF + WP2SZ)  // 1844352 ushorts; *2 = 3688704 B (128B-mult)

__device__ __forceinline__ float sigm(float x) {
  return __builtin_amdgcn_rcpf(1.0f + __expf(-x));
}
__device__ __forceinline__ float tanh_fast(float x) {
  float xc = fminf(fmaxf(x, -10.f), 10.f);
  float e = __expf(2.f * xc);
  return (e - 1.f) * __builtin_amdgcn_rcpf(e + 1.f);
}
__device__ __forceinline__ ushort_t f2u(f16 v) { return __builtin_bit_cast(ushort_t, v); }
__device__ __forceinline__ f16x8 u2f(uint4 v) { return __builtin_bit_cast(f16x8, v); }

// ---- init: pack weights (hi/lo, h1@c0 x@c32 order), fcw transpose, x[0] ----
__global__ __launch_bounds__(256) void pack_kernel(const float* __restrict__ w1,
                                                   const float* __restrict__ w2,
                                                   const float* __restrict__ fcb,
                                                   const float* __restrict__ x0,
                                                   const float* __restrict__ fcw,
                                                   float* __restrict__ pose,
                                                   ushort_t* __restrict__ wp1,
                                                   ushort_t* __restrict__ wp2,
                                                   ushort_t* __restrict__ in1hi0,
                                                   float* __restrict__ fcwp) {
  int i = blockIdx.x * 256 + threadIdx.x;
  if (i < 55296) {  // wp2: thread per (f, hl, lane), 8 elems each
    int lane = i & 63;
    int r0 = i >> 6;        // [0, 864)
    int hl = r0 & 1;
    int f = r0 >> 1;        // [0, 432) = (mb*27+s)*8+mt
    int mt = f & 7;
    int sm = f >> 3;        // [0,54)
    int s = sm % 27, mb = sm / 27;
    int m = mt * 16 + (lane & 15);
    int rg = mb * 128 + m;
    int h = rg >> 2, G = rg & 3;
    int orow = G * 64 + h;
    int tap = s / 3, cb = (s % 3) * 32;
    int cq = cb + (lane >> 4) * 8;
    for (int j = 0; j < 8; ++j) {
      float v = w2[(orow * 96 + cq + j) * 9 + tap];
      f16 vh = (f16)v;
      f16 vl = (f16)(v - (float)vh);
      wp2[(f * 2 + hl) * 512 + lane * 8 + j] = f2u(hl ? vl : vh);
    }
    return;
  }
  i -= 55296;
  if (i < 18432) {  // wp1 (channel order: c0-31 = h1 (ref 3+c), c32-34 = x)
    int lane = i & 63;
    int r0 = i >> 6;        // [0,288)
    int hl = r0 & 1;
    int f = r0 >> 1;        // [0,144) = (mb*18+s)*4+mt
    int mt = f & 3;
    int sm = f >> 2;        // [0,36)
    int s = sm % 18, mb = sm / 18;
    int m = mt * 16 + (lane & 15);
    int rg = mb * 64 + m;
    int h = rg >> 2, G = rg & 3;
    int orow = G * 32 + h;
    int tap = s >> 1, cb = (s & 1) * 32;
    int cq = cb + (lane >> 4) * 8;
    for (int j = 0; j < 8; ++j) {
      int c = cq + j;
      float v = 0.f;
      if (c < 32) v = w1[(orow * 35 + c + 3) * 9 + tap];
      else if (c < 35) v = w1[(orow * 35 + c - 32) * 9 + tap];
      f16 vh = (f16)v;
      f16 vl = (f16)(v - (float)vh);
      wp1[(f * 2 + hl) * 512 + lane * 8 + j] = f2u(hl ? vl : vh);
    }
    return;
  }
  i -= 18432;
  if (i < 768) { pose[i] = fcb[i % 6]; return; }
  i -= 768;
  if (i < 12288) {  // x[0] -> in1[0] c32-34
    int c = i >> 12, pix = i & 4095;
    int y = pix >> 6, x = pix & 63;
    int pidx = ((y + 1) * 66 + (x + 1)) * 48 + 32 + c;
    in1hi0[pidx] = f2u((f16)x0[i]);
    return;
  }
  i -= 12288;
  if (i < 262144) {  // fcw transpose: fcwp[cidx*6+j] = fcw[j*262144+cidx]
    float* dst = fcwp + (size_t)i * 6;
#pragma unroll
    for (int j = 0; j < 6; ++j) dst[j] = fcw[(size_t)j * 262144 + i];
  }
}

// ---- one ConvLSTM step for one layer (device body) ----
// bid in [0,256) = 2 M-blocks x 128 pixel tiles (4y x 8x); block 256 = 4 waves.
// L1: input = bhi (in1: h1@c0-31, x@c32-34). Writes d1 = in1-next, d2 = in2a.
// L2: input = bhi (in2a, 32ch) + b2hi (in2b, 64ch). Writes d1 = in2b.
template <int LAYER>
__device__ __forceinline__ void conv_body(
    int bid,
    const ushort_t* __restrict__ bhi, const ushort_t* __restrict__ b2hi,
    const ushort_t* __restrict__ wp, const float* __restrict__ bias,
    float* __restrict__ cst, float* __restrict__ hout,              // fp32 c (in-place), h
    ushort_t* __restrict__ d1hi,                                    // primary dest
    ushort_t* __restrict__ d2hi,                                    // secondary (L1 only)
    const float* __restrict__ fcwp, float* __restrict__ pose_t,     // L2 only
    const float* __restrict__ xn,                                   // L1 only: x[t+1]
    ushort_t* Bh, float* zs, ushort_t* hs, float (*red)[6]) {
  constexpr int CS = (LAYER == 1) ? 72 : 104;   // LDS c-stride (bank-conflict pad)
  constexpr int NC32 = (LAYER == 1) ? 2 : 3;    // 32-channel chunks
  constexpr int NS = 9 * NC32;                  // k32 steps
  constexpr int MT = (LAYER == 1) ? 4 : 8;      // 16-row m-tiles per block
  constexpr int MTPW = (LAYER == 1) ? 1 : 2;    // m-tiles per wave
  constexpr int H = (LAYER == 1) ? 32 : 64;
  constexpr int ZS = 33;                        // z LDS stride (pad)
  constexpr int DEPTH = 5;                      // A-frag register ring
  constexpr int PRE = DEPTH - 1;

  const int tid = threadIdx.x;
  const int lane = tid & 63;
  const int w = tid >> 6;
  const int mb = bid & 1;
  const int ntile = bid >> 1;
  const int Y0 = (ntile >> 3) * 4;
  const int X0 = (ntile & 7) * 8;

  // ---- A-frag register ring (weight hi+lo): issue loads EARLY ----
  const ushort_t* aptr[MTPW];
#pragma unroll
  for (int m = 0; m < MTPW; ++m) {
    int f = (mb * NS) * MT + (w * MTPW + m);
    aptr[m] = wp + f * 1024 + lane * 8;
  }
  uint4 A[DEPTH][MTPW][2];
  auto loada = [&](int s) {
#pragma unroll
    for (int m = 0; m < MTPW; ++m) {
      const ushort_t* p = aptr[m] + (size_t)s * (MT * 1024);
      A[s % DEPTH][m][0] = *(const uint4*)(p);
      A[s % DEPTH][m][1] = *(const uint4*)(p + 512);
    }
  };
#pragma unroll
  for (int s = 0; s < PRE; ++s) loada(s);

  // ---- stage halo slab [6y][10x][C] into LDS (normal cached loads) ----
  if (LAYER == 2) {
    for (int i = tid; i < 720; i += 256) {
      int hy = i / 120, rem = i % 120;
      int hx = rem / 12, c8 = rem % 12;
      int pos = (Y0 + hy) * 66 + X0 + hx;
      int dst = (hy * 10 + hx) * CS + c8 * 8;
      if (c8 < 4) {  // c0-31 from in2a (h1)
        *(uint4*)(&Bh[dst]) = *(const uint4*)(&bhi[pos * 32 + c8 * 8]);
      } else {       // c32-95 from in2b (h2)
        *(uint4*)(&Bh[dst]) = *(const uint4*)(&b2hi[pos * 64 + (c8 - 4) * 8]);
      }
    }
  } else {
    for (int i = tid; i < 360; i += 256) {
      int hy = i / 60, rem = i % 60;
      int hx = rem / 6, c8 = (rem % 6) * 8;
      int src = ((Y0 + hy) * 66 + X0 + hx) * 48 + c8;
      int dst = (hy * 10 + hx) * CS + c8;
      *(uint4*)(&Bh[dst]) = *(const uint4*)(&bhi[src]);
    }
    for (int i = tid; i < 120; i += 256) {  // zero-pad c 48..63 (read by frags)
      int hp = i >> 1;
      int dst = hp * CS + 48 + (i & 1) * 8;
      *(uint4*)(&Bh[dst]) = uint4{0, 0, 0, 0};
    }
  }
  __syncthreads();

  // ---- K-loop: A frags from registers (ring-prefetched), B frags from LDS ----
  const int n = lane & 15;
  const int q = lane >> 4;
  const int py = n >> 3, px = n & 7;

  f32x4 acc[MTPW][2];
#pragma unroll
  for (int m = 0; m < MTPW; ++m)
#pragma unroll
    for (int nt = 0; nt < 2; ++nt) acc[m][nt] = f32x4{0.f, 0.f, 0.f, 0.f};

#pragma unroll
  for (int s = 0; s < NS; ++s) {
    // rolling prefetch: writes ring slot consumed LAST iteration (WAR-bounded)
    if (s + PRE < NS) loada(s + PRE);
    const int tap = s / NC32, cc = s % NC32;
    const int ty = tap / 3, tx = tap % 3;
    const int coff = cc * 32 + q * 8;
    f16x8 bfh[2];
#pragma unroll
    for (int nt = 0; nt < 2; ++nt) {
      int hp = (py + nt * 2 + ty) * 10 + (px + tx);
      bfh[nt] = u2f(*(const uint4*)(&Bh[hp * CS + coff]));
    }
#pragma unroll
    for (int m = 0; m < MTPW; ++m) {
      f16x8 ah = u2f(A[s % DEPTH][m][0]);
      f16x8 al = u2f(A[s % DEPTH][m][1]);
#pragma unroll
      for (int nt = 0; nt < 2; ++nt) {
        acc[m][nt] = __builtin_amdgcn_mfma_f32_16x16x32_f16(ah, bfh[nt], acc[m][nt], 0, 0, 0);
        acc[m][nt] = __builtin_amdgcn_mfma_f32_16x16x32_f16(al, bfh[nt], acc[m][nt], 0, 0, 0);
      }
    }
  }

  // ---- z exchange through LDS ----
#pragma unroll
  for (int m = 0; m < MTPW; ++m) {
    int mt = w * MTPW + m;
#pragma unroll
    for (int nt = 0; nt < 2; ++nt)
#pragma unroll
      for (int i = 0; i < 4; ++i) zs[(mt * 16 + q * 4 + i) * ZS + nt * 16 + n] = acc[m][nt][i];
  }
  __syncthreads();

  // ---- LSTM cell + f32 state writes; hh staged into LDS (+ FC fuse L2) ----
  constexpr int NCELL = (MT * 4 * 32) / 256;  // cells per thread (L2: 4, L1: 2)
  float p6[6] = {0, 0, 0, 0, 0, 0};
#pragma unroll
  for (int i = 0; i < NCELL; ++i) {
    int idx = i * 256 + tid;
    int ch = idx >> 5, pI = idx & 31;
    float zi = zs[(ch * 4 + 0) * ZS + pI];
    float zf = zs[(ch * 4 + 1) * ZS + pI];
    float zo = zs[(ch * 4 + 2) * ZS + pI];
    float zg = zs[(ch * 4 + 3) * ZS + pI];
    int hg = mb * (MT * 4) + ch;
    zi += bias[0 * H + hg];
    zf += bias[1 * H + hg];
    zo += bias[2 * H + hg];
    zg += bias[3 * H + hg];
    int y = Y0 + (pI >> 3), x = X0 + (pI & 7);
    int cidx = hg * 4096 + y * 64 + x;
    float cold = cst[cidx];
    float cn = sigm(zf) * cold + sigm(zi) * tanh_fast(zg);
    float hn = sigm(zo) * tanh_fast(cn);
    cst[cidx] = cn;
    hout[cidx] = hn;
    hs[pI * 36 + ch] = f2u((f16)hn);
    if (LAYER == 2) {
#pragma unroll
      for (int j = 0; j < 6; ++j) p6[j] += hn * fcwp[(size_t)cidx * 6 + j];
    }
  }
  __syncthreads();  // hs complete

  // ---- coalesced h-staging stores (plain 8B stores, full 32B granules) ----
  if (LAYER == 2) {
    int pxi = tid & 31, g = tid >> 5;   // 32 px x 8 ch-groups of 4
    int y = Y0 + (pxi >> 3), x = X0 + (pxi & 7);
    int pidx = (y + 1) * 66 + (x + 1);
    u64_t v = *(const u64_t*)&hs[pxi * 36 + g * 4];
    *(u64_t*)&d1hi[pidx * 64 + mb * 32 + g * 4] = v;   // in2b: h2
  } else {
    int t2 = tid & 127;
    int pxi = t2 & 31, g = t2 >> 5;     // 32 px x 4 ch-groups of 4
    int y = Y0 + (pxi >> 3), x = X0 + (pxi & 7);
    int pidx = (y + 1) * 66 + (x + 1);
    u64_t v = *(const u64_t*)&hs[pxi * 36 + g * 4];
    if (tid < 128) {
      *(u64_t*)&d2hi[pidx * 32 + mb * 16 + g * 4] = v; // in2a: h1
    } else {
      *(u64_t*)&d1hi[pidx * 48 + mb * 16 + g * 4] = v; // in1-next: h1 @c0
    }
    // stage x[t+1] into in1 next-parity (c32-34; granule c32-47 mb0-only)
    if (mb == 0 && tid < 32) {
      int yy = Y0 + (tid >> 3), xx = X0 + (tid & 7);
      int pidx2 = (yy + 1) * 66 + (xx + 1);
#pragma unroll
      for (int c = 0; c < 3; ++c) {
        d1hi[pidx2 * 48 + 32 + c] = f2u((f16)xn[c * 4096 + yy * 64 + xx]);
      }
    }
  }

  if (LAYER == 2) {
#pragma unroll
    for (int j = 0; j < 6; ++j)
#pragma unroll
      for (int off = 32; off > 0; off >>= 1) p6[j] += __shfl_xor(p6[j], off, 64);
    if (lane == 0)
#pragma unroll
      for (int j = 0; j < 6; ++j) red[w][j] = p6[j];
    __syncthreads();
    if (tid < 6) atomicAdd(pose_t + tid, red[0][tid] + red[1][tid] + red[2][tid] + red[3][tid]);
  }
}

// ---- fused temporal-skew kernel: blocks 0-255 = L1[t], 256-511 = L2[t-1] ----
__global__ __launch_bounds__(256, 2) void fused_step(
    int t,
    const ushort_t* __restrict__ i1rhi, ushort_t* __restrict__ i1whi,
    const ushort_t* __restrict__ i2arhi, const ushort_t* __restrict__ i2brhi,
    ushort_t* __restrict__ i2awhi, ushort_t* __restrict__ i2bwhi,
    const ushort_t* __restrict__ wp1, const ushort_t* __restrict__ wp2,
    const float* __restrict__ b1, const float* __restrict__ b2,
    float* __restrict__ c1o, float* __restrict__ h1o,
    float* __restrict__ c2o, float* __restrict__ h2o,
    const float* __restrict__ fcwp, float* __restrict__ pose_t,
    const float* __restrict__ xn) {
  // union'd shared memory: max over both roles (L2 sizes), ~31.5 KB
  __shared__ __align__(16) ushort_t Bh[6240];   // max(60*72, 60*104)
  __shared__ float zs[4224];                    // max(64,128)*33
  __shared__ __align__(8) ushort_t hs[1152];    // 32px * 36-stride hh stage
  __shared__ float red[4][6];

  int bid = blockIdx.x;
  if (bid < 256) {
    if (t >= 128) return;
    conv_body<1>(bid, i1rhi, nullptr, wp1, b1, c1o, h1o,
                 i1whi,                 // h1 -> in1 next @c0 (+ x[t+1] @c32)
                 i2awhi,                // h1 -> in2a[t&1]
                 nullptr, nullptr, xn, Bh, zs, hs, red);
  } else {
    if (t < 1) return;
    conv_body<2>(bid - 256, i2arhi, i2brhi, wp2, b2, c2o, h2o,
                 i2bwhi,                // h2 -> in2b[t&1]
                 nullptr,
                 fcwp, pose_t, nullptr, Bh, zs, hs, red);
  }
}

extern "C" void kernel_launch(void* const* d_in, const int* in_sizes, int n_in, void* d_out,
                              int out_size, void* d_ws, size_t ws_size, hipStream_t stream) {
  const float* input = (const float*)d_in[0];
  const float* w1 = (const float*)d_in[1];
  const float* b1 = (const float*)d_in[2];
  const float* w2 = (const float*)d_in[3];
  const float* b2 = (const float*)d_in[4];
  const float* fcw = (const float*)d_in[5];
  const float* fcb = (const float*)d_in[6];

  float* out = (float*)d_out;
  float* pose = out;
  float* h1o = out + 768;
  float* c1o = h1o + 131072;
  float* h2o = c1o + 131072;
  float* c2o = h2o + 262144;

  ushort_t* ws = (ushort_t*)d_ws;
  ushort_t* in1hi[2] = {ws, ws + IN1SZ};
  ushort_t* ab = ws + 2 * IN1SZ;
  ushort_t* i2ahi[2] = {ab, ab + IN2ASZ};
  ushort_t* bb = ab + 2 * IN2ASZ;
  ushort_t* i2bhi[2] = {bb, bb + IN2BSZ};
  ushort_t* wp1 = ws + WP1OFF;
  ushort_t* wp2 = ws + WP2OFF;
  float* fcwp = (float*)(ws + FCWPOFF);  // 6.29 MB

  // zero state buffers (t=0 h-states + padded borders)
  hipMemsetAsync(ws, 0, (size_t)WP1OFF * 2, stream);
  hipMemsetAsync(out + 768, 0, (size_t)786432 * 4, stream);
  pack_kernel<<<1363, 256, 0, stream>>>(w1, w2, fcb, input, fcw, pose, wp1, wp2,
                                        in1hi[0], fcwp);

  // K_t: L1[t] (t<128) + L2[t-1] (t>=1).
  //   L1[t]: reads in1[t&1]; writes in1[(t+1)&1] (h1@c0 + x[t+1]@c32) and in2a[t&1].
  //   L2[t-1]: reads in2a/in2b[(t-1)&1]; writes in2b[t&1].
  for (int t = 0; t <= 128; ++t) {
    int p = t & 1, pn = p ^ 1;
    int tn = (t + 1 < 128) ? t + 1 : 127;
    float* pose_t = pose + ((t > 0) ? (t - 1) * 6 : 0);
    fused_step<<<512, 256, 0, stream>>>(
        t,
        in1hi[p], in1hi[pn],
        i2ahi[pn], i2bhi[pn],   // (t-1)&1 == pn
        i2ahi[p], i2bhi[p],
        wp1, wp2, b1, b2, c1o, h1o, c2o, h2o,
        fcwp, pose_t,
        input + (size_t)tn * 12288);
  }
}

// Round 10
// 1680.840 us; speedup vs baseline: 5.6762x; 1.3652x over previous
//
#include <hip/hip_runtime.h>

typedef _Float16 f16;
typedef _Float16 f16x8 __attribute__((ext_vector_type(8)));
typedef float f32x4 __attribute__((ext_vector_type(4)));
typedef unsigned short ushort_t;
typedef unsigned long long u64_t;

// ---------------------------------------------------------------------------
// PoseConvLSTM via implicit-GEMM MFMA. Multi-launch temporal-skew fusion.
//
// Round 10: weights hi-only f16 (drop the weight-lo stream). Round 9 = 2295us;
// arithmetic says weight L2 streaming is the dominant in-body term:
// 147 MB/step (hi+lo) = ~575 KB/CU @ ~56 B/cyc/CU ~= 4.3 us/step on 2 waves/
// SIMD. Hi-only halves that, halves MFMA count (1 per product), and halves
// A-ring register pressure (r9's VGPR=44 shows the compiler collapsed the
// hi+lo ring; DEPTH raised 5->8 now that slots are 16B).
// Error budget: weight-rounding ~2e-4/gate/step, same magnitude as the
// input-lo term dropped in r4 (absmax 1.95e-3 -> 1.56e-2). Expect ~2-3.5e-2
// vs threshold 6.31e-2. If it fails, revert to r9 + 64px tiling.
//
// Kernel K_t: blocks 0-255 = L1[t], blocks 256-511 = L2[t-1] (temporal skew,
// no intra-kernel dependency). All stores NORMAL (kernel-boundary coherence);
// concurrent writers own disjoint 32B granules (r2/r3 lesson).
//   in1[parity]:  [66][66][48]  h1prev c0-31, x[t] c32-34, 0 c35-47 (L1-writ)
//   in2a[parity]: [66][66][32]  h1[t]   (L1-written only)
//   in2b[parity]: [66][66][64]  h2[t-1] (L2-written only)
// fcwp[cidx*6+j] f32 transpose-pack (r9); LDS-transposed 8B h-stores (r9).
//
// d_out (floats): pose[768] | h1[131072] | c1[131072] | h2[262144] | c2[262144]
// ---------------------------------------------------------------------------

#define IN1SZ 209088    // 66*66*48
#define IN2ASZ 139392   // 66*66*32
#define IN2BSZ 278784   // 66*66*64
#define WP1OFF 1254528  // ushort offset of wp1 (2*IN1SZ + 2*IN2ASZ + 2*IN2BSZ)
#define WP1SZ 73728     // 2mb*18s*4mt*512 (hi only)
#define WP2OFF (WP1OFF + WP1SZ)
#define WP2SZ 221184    // 2mb*27s*8mt*512 (hi only)
#define FCWPOFF (WP2OFF + WP2SZ)  // 1549440 ushorts; *2 = 3098880 B (128B-mult)

__device__ __forceinline__ float sigm(float x) {
  return __builtin_amdgcn_rcpf(1.0f + __expf(-x));
}
__device__ __forceinline__ float tanh_fast(float x) {
  float xc = fminf(fmaxf(x, -10.f), 10.f);
  float e = __expf(2.f * xc);
  return (e - 1.f) * __builtin_amdgcn_rcpf(e + 1.f);
}
__device__ __forceinline__ ushort_t f2u(f16 v) { return __builtin_bit_cast(ushort_t, v); }
__device__ __forceinline__ f16x8 u2f(uint4 v) { return __builtin_bit_cast(f16x8, v); }

// ---- init: pack weights (hi-only, h1@c0 x@c32 order), fcw transpose, x[0] ----
__global__ __launch_bounds__(256) void pack_kernel(const float* __restrict__ w1,
                                                   const float* __restrict__ w2,
                                                   const float* __restrict__ fcb,
                                                   const float* __restrict__ x0,
                                                   const float* __restrict__ fcw,
                                                   float* __restrict__ pose,
                                                   ushort_t* __restrict__ wp1,
                                                   ushort_t* __restrict__ wp2,
                                                   ushort_t* __restrict__ in1hi0,
                                                   float* __restrict__ fcwp) {
  int i = blockIdx.x * 256 + threadIdx.x;
  if (i < 27648) {  // wp2: thread per (f, lane), 8 elems each
    int lane = i & 63;
    int f = i >> 6;         // [0, 432) = (mb*27+s)*8+mt
    int mt = f & 7;
    int sm = f >> 3;        // [0,54)
    int s = sm % 27, mb = sm / 27;
    int m = mt * 16 + (lane & 15);
    int rg = mb * 128 + m;
    int h = rg >> 2, G = rg & 3;
    int orow = G * 64 + h;
    int tap = s / 3, cb = (s % 3) * 32;
    int cq = cb + (lane >> 4) * 8;
    for (int j = 0; j < 8; ++j) {
      float v = w2[(orow * 96 + cq + j) * 9 + tap];
      wp2[f * 512 + lane * 8 + j] = f2u((f16)v);
    }
    return;
  }
  i -= 27648;
  if (i < 9216) {  // wp1 (channel order: c0-31 = h1 (ref 3+c), c32-34 = x)
    int lane = i & 63;
    int f = i >> 6;         // [0,144) = (mb*18+s)*4+mt
    int mt = f & 3;
    int sm = f >> 2;        // [0,36)
    int s = sm % 18, mb = sm / 18;
    int m = mt * 16 + (lane & 15);
    int rg = mb * 64 + m;
    int h = rg >> 2, G = rg & 3;
    int orow = G * 32 + h;
    int tap = s >> 1, cb = (s & 1) * 32;
    int cq = cb + (lane >> 4) * 8;
    for (int j = 0; j < 8; ++j) {
      int c = cq + j;
      float v = 0.f;
      if (c < 32) v = w1[(orow * 35 + c + 3) * 9 + tap];
      else if (c < 35) v = w1[(orow * 35 + c - 32) * 9 + tap];
      wp1[f * 512 + lane * 8 + j] = f2u((f16)v);
    }
    return;
  }
  i -= 9216;
  if (i < 768) { pose[i] = fcb[i % 6]; return; }
  i -= 768;
  if (i < 12288) {  // x[0] -> in1[0] c32-34
    int c = i >> 12, pix = i & 4095;
    int y = pix >> 6, x = pix & 63;
    int pidx = ((y + 1) * 66 + (x + 1)) * 48 + 32 + c;
    in1hi0[pidx] = f2u((f16)x0[i]);
    return;
  }
  i -= 12288;
  if (i < 262144) {  // fcw transpose: fcwp[cidx*6+j] = fcw[j*262144+cidx]
    float* dst = fcwp + (size_t)i * 6;
#pragma unroll
    for (int j = 0; j < 6; ++j) dst[j] = fcw[(size_t)j * 262144 + i];
  }
}

// ---- one ConvLSTM step for one layer (device body) ----
// bid in [0,256) = 2 M-blocks x 128 pixel tiles (4y x 8x); block 256 = 4 waves.
// L1: input = bhi (in1: h1@c0-31, x@c32-34). Writes d1 = in1-next, d2 = in2a.
// L2: input = bhi (in2a, 32ch) + b2hi (in2b, 64ch). Writes d1 = in2b.
template <int LAYER>
__device__ __forceinline__ void conv_body(
    int bid,
    const ushort_t* __restrict__ bhi, const ushort_t* __restrict__ b2hi,
    const ushort_t* __restrict__ wp, const float* __restrict__ bias,
    float* __restrict__ cst, float* __restrict__ hout,              // fp32 c (in-place), h
    ushort_t* __restrict__ d1hi,                                    // primary dest
    ushort_t* __restrict__ d2hi,                                    // secondary (L1 only)
    const float* __restrict__ fcwp, float* __restrict__ pose_t,     // L2 only
    const float* __restrict__ xn,                                   // L1 only: x[t+1]
    ushort_t* Bh, float* zs, ushort_t* hs, float (*red)[6]) {
  constexpr int CS = (LAYER == 1) ? 72 : 104;   // LDS c-stride (bank-conflict pad)
  constexpr int NC32 = (LAYER == 1) ? 2 : 3;    // 32-channel chunks
  constexpr int NS = 9 * NC32;                  // k32 steps
  constexpr int MT = (LAYER == 1) ? 4 : 8;      // 16-row m-tiles per block
  constexpr int MTPW = (LAYER == 1) ? 1 : 2;    // m-tiles per wave
  constexpr int H = (LAYER == 1) ? 32 : 64;
  constexpr int ZS = 33;                        // z LDS stride (pad)
  constexpr int DEPTH = 8;                      // A-frag register ring (hi only)
  constexpr int PRE = DEPTH - 1;

  const int tid = threadIdx.x;
  const int lane = tid & 63;
  const int w = tid >> 6;
  const int mb = bid & 1;
  const int ntile = bid >> 1;
  const int Y0 = (ntile >> 3) * 4;
  const int X0 = (ntile & 7) * 8;

  // ---- A-frag register ring (weight hi only): issue loads EARLY ----
  const ushort_t* aptr[MTPW];
#pragma unroll
  for (int m = 0; m < MTPW; ++m) {
    int f = (mb * NS) * MT + (w * MTPW + m);
    aptr[m] = wp + f * 512 + lane * 8;
  }
  uint4 A[DEPTH][MTPW];
  auto loada = [&](int s) {
#pragma unroll
    for (int m = 0; m < MTPW; ++m) {
      A[s % DEPTH][m] = *(const uint4*)(aptr[m] + (size_t)s * (MT * 512));
    }
  };
#pragma unroll
  for (int s = 0; s < PRE; ++s) loada(s);

  // ---- stage halo slab [6y][10x][C] into LDS (normal cached loads) ----
  if (LAYER == 2) {
    for (int i = tid; i < 720; i += 256) {
      int hy = i / 120, rem = i % 120;
      int hx = rem / 12, c8 = rem % 12;
      int pos = (Y0 + hy) * 66 + X0 + hx;
      int dst = (hy * 10 + hx) * CS + c8 * 8;
      if (c8 < 4) {  // c0-31 from in2a (h1)
        *(uint4*)(&Bh[dst]) = *(const uint4*)(&bhi[pos * 32 + c8 * 8]);
      } else {       // c32-95 from in2b (h2)
        *(uint4*)(&Bh[dst]) = *(const uint4*)(&b2hi[pos * 64 + (c8 - 4) * 8]);
      }
    }
  } else {
    for (int i = tid; i < 360; i += 256) {
      int hy = i / 60, rem = i % 60;
      int hx = rem / 6, c8 = (rem % 6) * 8;
      int src = ((Y0 + hy) * 66 + X0 + hx) * 48 + c8;
      int dst = (hy * 10 + hx) * CS + c8;
      *(uint4*)(&Bh[dst]) = *(const uint4*)(&bhi[src]);
    }
    for (int i = tid; i < 120; i += 256) {  // zero-pad c 48..63 (read by frags)
      int hp = i >> 1;
      int dst = hp * CS + 48 + (i & 1) * 8;
      *(uint4*)(&Bh[dst]) = uint4{0, 0, 0, 0};
    }
  }
  __syncthreads();

  // ---- K-loop: A frags from registers (ring-prefetched), B frags from LDS ----
  const int n = lane & 15;
  const int q = lane >> 4;
  const int py = n >> 3, px = n & 7;

  f32x4 acc[MTPW][2];
#pragma unroll
  for (int m = 0; m < MTPW; ++m)
#pragma unroll
    for (int nt = 0; nt < 2; ++nt) acc[m][nt] = f32x4{0.f, 0.f, 0.f, 0.f};

#pragma unroll
  for (int s = 0; s < NS; ++s) {
    // rolling prefetch: writes ring slot consumed LAST iteration (WAR-bounded)
    if (s + PRE < NS) loada(s + PRE);
    const int tap = s / NC32, cc = s % NC32;
    const int ty = tap / 3, tx = tap % 3;
    const int coff = cc * 32 + q * 8;
    f16x8 bfh[2];
#pragma unroll
    for (int nt = 0; nt < 2; ++nt) {
      int hp = (py + nt * 2 + ty) * 10 + (px + tx);
      bfh[nt] = u2f(*(const uint4*)(&Bh[hp * CS + coff]));
    }
#pragma unroll
    for (int m = 0; m < MTPW; ++m) {
      f16x8 ah = u2f(A[s % DEPTH][m]);
#pragma unroll
      for (int nt = 0; nt < 2; ++nt) {
        acc[m][nt] = __builtin_amdgcn_mfma_f32_16x16x32_f16(ah, bfh[nt], acc[m][nt], 0, 0, 0);
      }
    }
  }

  // ---- z exchange through LDS ----
#pragma unroll
  for (int m = 0; m < MTPW; ++m) {
    int mt = w * MTPW + m;
#pragma unroll
    for (int nt = 0; nt < 2; ++nt)
#pragma unroll
      for (int i = 0; i < 4; ++i) zs[(mt * 16 + q * 4 + i) * ZS + nt * 16 + n] = acc[m][nt][i];
  }
  __syncthreads();

  // ---- LSTM cell + f32 state writes; hh staged into LDS (+ FC fuse L2) ----
  constexpr int NCELL = (MT * 4 * 32) / 256;  // cells per thread (L2: 4, L1: 2)
  float p6[6] = {0, 0, 0, 0, 0, 0};
#pragma unroll
  for (int i = 0; i < NCELL; ++i) {
    int idx = i * 256 + tid;
    int ch = idx >> 5, pI = idx & 31;
    float zi = zs[(ch * 4 + 0) * ZS + pI];
    float zf = zs[(ch * 4 + 1) * ZS + pI];
    float zo = zs[(ch * 4 + 2) * ZS + pI];
    float zg = zs[(ch * 4 + 3) * ZS + pI];
    int hg = mb * (MT * 4) + ch;
    zi += bias[0 * H + hg];
    zf += bias[1 * H + hg];
    zo += bias[2 * H + hg];
    zg += bias[3 * H + hg];
    int y = Y0 + (pI >> 3), x = X0 + (pI & 7);
    int cidx = hg * 4096 + y * 64 + x;
    float cold = cst[cidx];
    float cn = sigm(zf) * cold + sigm(zi) * tanh_fast(zg);
    float hn = sigm(zo) * tanh_fast(cn);
    cst[cidx] = cn;
    hout[cidx] = hn;
    hs[pI * 36 + ch] = f2u((f16)hn);
    if (LAYER == 2) {
#pragma unroll
      for (int j = 0; j < 6; ++j) p6[j] += hn * fcwp[(size_t)cidx * 6 + j];
    }
  }
  __syncthreads();  // hs complete

  // ---- coalesced h-staging stores (plain 8B stores, full 32B granules) ----
  if (LAYER == 2) {
    int pxi = tid & 31, g = tid >> 5;   // 32 px x 8 ch-groups of 4
    int y = Y0 + (pxi >> 3), x = X0 + (pxi & 7);
    int pidx = (y + 1) * 66 + (x + 1);
    u64_t v = *(const u64_t*)&hs[pxi * 36 + g * 4];
    *(u64_t*)&d1hi[pidx * 64 + mb * 32 + g * 4] = v;   // in2b: h2
  } else {
    int t2 = tid & 127;
    int pxi = t2 & 31, g = t2 >> 5;     // 32 px x 4 ch-groups of 4
    int y = Y0 + (pxi >> 3), x = X0 + (pxi & 7);
    int pidx = (y + 1) * 66 + (x + 1);
    u64_t v = *(const u64_t*)&hs[pxi * 36 + g * 4];
    if (tid < 128) {
      *(u64_t*)&d2hi[pidx * 32 + mb * 16 + g * 4] = v; // in2a: h1
    } else {
      *(u64_t*)&d1hi[pidx * 48 + mb * 16 + g * 4] = v; // in1-next: h1 @c0
    }
    // stage x[t+1] into in1 next-parity (c32-34; granule c32-47 mb0-only)
    if (mb == 0 && tid < 32) {
      int yy = Y0 + (tid >> 3), xx = X0 + (tid & 7);
      int pidx2 = (yy + 1) * 66 + (xx + 1);
#pragma unroll
      for (int c = 0; c < 3; ++c) {
        d1hi[pidx2 * 48 + 32 + c] = f2u((f16)xn[c * 4096 + yy * 64 + xx]);
      }
    }
  }

  if (LAYER == 2) {
#pragma unroll
    for (int j = 0; j < 6; ++j)
#pragma unroll
      for (int off = 32; off > 0; off >>= 1) p6[j] += __shfl_xor(p6[j], off, 64);
    if (lane == 0)
#pragma unroll
      for (int j = 0; j < 6; ++j) red[w][j] = p6[j];
    __syncthreads();
    if (tid < 6) atomicAdd(pose_t + tid, red[0][tid] + red[1][tid] + red[2][tid] + red[3][tid]);
  }
}

// ---- fused temporal-skew kernel: blocks 0-255 = L1[t], 256-511 = L2[t-1] ----
__global__ __launch_bounds__(256, 2) void fused_step(
    int t,
    const ushort_t* __restrict__ i1rhi, ushort_t* __restrict__ i1whi,
    const ushort_t* __restrict__ i2arhi, const ushort_t* __restrict__ i2brhi,
    ushort_t* __restrict__ i2awhi, ushort_t* __restrict__ i2bwhi,
    const ushort_t* __restrict__ wp1, const ushort_t* __restrict__ wp2,
    const float* __restrict__ b1, const float* __restrict__ b2,
    float* __restrict__ c1o, float* __restrict__ h1o,
    float* __restrict__ c2o, float* __restrict__ h2o,
    const float* __restrict__ fcwp, float* __restrict__ pose_t,
    const float* __restrict__ xn) {
  // union'd shared memory: max over both roles (L2 sizes), ~31.5 KB
  __shared__ __align__(16) ushort_t Bh[6240];   // max(60*72, 60*104)
  __shared__ float zs[4224];                    // max(64,128)*33
  __shared__ __align__(8) ushort_t hs[1152];    // 32px * 36-stride hh stage
  __shared__ float red[4][6];

  int bid = blockIdx.x;
  if (bid < 256) {
    if (t >= 128) return;
    conv_body<1>(bid, i1rhi, nullptr, wp1, b1, c1o, h1o,
                 i1whi,                 // h1 -> in1 next @c0 (+ x[t+1] @c32)
                 i2awhi,                // h1 -> in2a[t&1]
                 nullptr, nullptr, xn, Bh, zs, hs, red);
  } else {
    if (t < 1) return;
    conv_body<2>(bid - 256, i2arhi, i2brhi, wp2, b2, c2o, h2o,
                 i2bwhi,                // h2 -> in2b[t&1]
                 nullptr,
                 fcwp, pose_t, nullptr, Bh, zs, hs, red);
  }
}

extern "C" void kernel_launch(void* const* d_in, const int* in_sizes, int n_in, void* d_out,
                              int out_size, void* d_ws, size_t ws_size, hipStream_t stream) {
  const float* input = (const float*)d_in[0];
  const float* w1 = (const float*)d_in[1];
  const float* b1 = (const float*)d_in[2];
  const float* w2 = (const float*)d_in[3];
  const float* b2 = (const float*)d_in[4];
  const float* fcw = (const float*)d_in[5];
  const float* fcb = (const float*)d_in[6];

  float* out = (float*)d_out;
  float* pose = out;
  float* h1o = out + 768;
  float* c1o = h1o + 131072;
  float* h2o = c1o + 131072;
  float* c2o = h2o + 262144;

  ushort_t* ws = (ushort_t*)d_ws;
  ushort_t* in1hi[2] = {ws, ws + IN1SZ};
  ushort_t* ab = ws + 2 * IN1SZ;
  ushort_t* i2ahi[2] = {ab, ab + IN2ASZ};
  ushort_t* bb = ab + 2 * IN2ASZ;
  ushort_t* i2bhi[2] = {bb, bb + IN2BSZ};
  ushort_t* wp1 = ws + WP1OFF;
  ushort_t* wp2 = ws + WP2OFF;
  float* fcwp = (float*)(ws + FCWPOFF);  // 6.29 MB

  // zero state buffers (t=0 h-states + padded borders)
  hipMemsetAsync(ws, 0, (size_t)WP1OFF * 2, stream);
  hipMemsetAsync(out + 768, 0, (size_t)786432 * 4, stream);
  pack_kernel<<<1219, 256, 0, stream>>>(w1, w2, fcb, input, fcw, pose, wp1, wp2,
                                        in1hi[0], fcwp);

  // K_t: L1[t] (t<128) + L2[t-1] (t>=1).
  //   L1[t]: reads in1[t&1]; writes in1[(t+1)&1] (h1@c0 + x[t+1]@c32) and in2a[t&1].
  //   L2[t-1]: reads in2a/in2b[(t-1)&1]; writes in2b[t&1].
  for (int t = 0; t <= 128; ++t) {
    int p = t & 1, pn = p ^ 1;
    int tn = (t + 1 < 128) ? t + 1 : 127;
    float* pose_t = pose + ((t > 0) ? (t - 1) * 6 : 0);
    fused_step<<<512, 256, 0, stream>>>(
        t,
        in1hi[p], in1hi[pn],
        i2ahi[pn], i2bhi[pn],   // (t-1)&1 == pn
        i2ahi[p], i2bhi[p],
        wp1, wp2, b1, b2, c1o, h1o, c2o, h2o,
        fcwp, pose_t,
        input + (size_t)tn * 12288);
  }
}

// Round 11
// 1565.271 us; speedup vs baseline: 6.0953x; 1.0738x over previous
//
#include <hip/hip_runtime.h>

typedef _Float16 f16;
typedef _Float16 f16x8 __attribute__((ext_vector_type(8)));
typedef float f32x4 __attribute__((ext_vector_type(4)));
typedef unsigned short ushort_t;
typedef unsigned long long u64_t;

// ---------------------------------------------------------------------------
// PoseConvLSTM via implicit-GEMM MFMA. Multi-launch temporal-skew fusion.
//
// Round 11: eliminate the zs LDS round-trip. The MFMA C/D layout
// (col=lane&15, row=(lane>>4)*4+reg) composed with the weight pack
// (orow=G*H+h, G=rg&3, mt*16==0 mod 4) means lane (n,q) of m-tile mt holds
// ALL FOUR GATES of cell (ch=mt*4+q, pixel=nt*16+n) in acc[m][nt][0..3].
// Proof: the r10 kernel's zs write (mt*16+q*4+i)*ZS+nt*16+n and read
// (ch*4+G)*ZS+pI indices are equal iff ch=mt*4+q, G=i. So the LSTM cell
// epilogue consumes acc directly: -32 LDS ops/thread, -1 syncthreads,
// -16.9 KB LDS (32.2 -> ~15 KB/block).
// Also: staging loads issued BEFORE A-ring prefill (staging is the critical
// path to the barrier); output memset skips h1 (h-states fully overwritten
// every step; only c-states need zero at t=0).
//
// Kernel K_t: blocks 0-255 = L1[t], blocks 256-511 = L2[t-1] (temporal skew,
// no intra-kernel dependency). All stores NORMAL (kernel-boundary coherence);
// concurrent writers own disjoint 32B granules (r2/r3 lesson).
//   in1[parity]:  [66][66][48]  h1prev c0-31, x[t] c32-34, 0 c35-47 (L1-writ)
//   in2a[parity]: [66][66][32]  h1[t]   (L1-written only)
//   in2b[parity]: [66][66][64]  h2[t-1] (L2-written only)
// Weights hi-only f16 (r10); fcwp[cidx*6+j] f32 transpose-pack (r9);
// LDS-transposed 8B h-stores (r9).
//
// d_out (floats): pose[768] | h1[131072] | c1[131072] | h2[262144] | c2[262144]
// ---------------------------------------------------------------------------

#define IN1SZ 209088    // 66*66*48
#define IN2ASZ 139392   // 66*66*32
#define IN2BSZ 278784   // 66*66*64
#define WP1OFF 1254528  // ushort offset of wp1 (2*IN1SZ + 2*IN2ASZ + 2*IN2BSZ)
#define WP1SZ 73728     // 2mb*18s*4mt*512 (hi only)
#define WP2OFF (WP1OFF + WP1SZ)
#define WP2SZ 221184    // 2mb*27s*8mt*512 (hi only)
#define FCWPOFF (WP2OFF + WP2SZ)  // 1549440 ushorts; *2 = 3098880 B (128B-mult)

__device__ __forceinline__ float sigm(float x) {
  return __builtin_amdgcn_rcpf(1.0f + __expf(-x));
}
__device__ __forceinline__ float tanh_fast(float x) {
  float xc = fminf(fmaxf(x, -10.f), 10.f);
  float e = __expf(2.f * xc);
  return (e - 1.f) * __builtin_amdgcn_rcpf(e + 1.f);
}
__device__ __forceinline__ ushort_t f2u(f16 v) { return __builtin_bit_cast(ushort_t, v); }
__device__ __forceinline__ f16x8 u2f(uint4 v) { return __builtin_bit_cast(f16x8, v); }

// ---- init: pack weights (hi-only, h1@c0 x@c32 order), fcw transpose, x[0] ----
__global__ __launch_bounds__(256) void pack_kernel(const float* __restrict__ w1,
                                                   const float* __restrict__ w2,
                                                   const float* __restrict__ fcb,
                                                   const float* __restrict__ x0,
                                                   const float* __restrict__ fcw,
                                                   float* __restrict__ pose,
                                                   ushort_t* __restrict__ wp1,
                                                   ushort_t* __restrict__ wp2,
                                                   ushort_t* __restrict__ in1hi0,
                                                   float* __restrict__ fcwp) {
  int i = blockIdx.x * 256 + threadIdx.x;
  if (i < 27648) {  // wp2: thread per (f, lane), 8 elems each
    int lane = i & 63;
    int f = i >> 6;         // [0, 432) = (mb*27+s)*8+mt
    int mt = f & 7;
    int sm = f >> 3;        // [0,54)
    int s = sm % 27, mb = sm / 27;
    int m = mt * 16 + (lane & 15);
    int rg = mb * 128 + m;
    int h = rg >> 2, G = rg & 3;
    int orow = G * 64 + h;
    int tap = s / 3, cb = (s % 3) * 32;
    int cq = cb + (lane >> 4) * 8;
    for (int j = 0; j < 8; ++j) {
      float v = w2[(orow * 96 + cq + j) * 9 + tap];
      wp2[f * 512 + lane * 8 + j] = f2u((f16)v);
    }
    return;
  }
  i -= 27648;
  if (i < 9216) {  // wp1 (channel order: c0-31 = h1 (ref 3+c), c32-34 = x)
    int lane = i & 63;
    int f = i >> 6;         // [0,144) = (mb*18+s)*4+mt
    int mt = f & 3;
    int sm = f >> 2;        // [0,36)
    int s = sm % 18, mb = sm / 18;
    int m = mt * 16 + (lane & 15);
    int rg = mb * 64 + m;
    int h = rg >> 2, G = rg & 3;
    int orow = G * 32 + h;
    int tap = s >> 1, cb = (s & 1) * 32;
    int cq = cb + (lane >> 4) * 8;
    for (int j = 0; j < 8; ++j) {
      int c = cq + j;
      float v = 0.f;
      if (c < 32) v = w1[(orow * 35 + c + 3) * 9 + tap];
      else if (c < 35) v = w1[(orow * 35 + c - 32) * 9 + tap];
      wp1[f * 512 + lane * 8 + j] = f2u((f16)v);
    }
    return;
  }
  i -= 9216;
  if (i < 768) { pose[i] = fcb[i % 6]; return; }
  i -= 768;
  if (i < 12288) {  // x[0] -> in1[0] c32-34
    int c = i >> 12, pix = i & 4095;
    int y = pix >> 6, x = pix & 63;
    int pidx = ((y + 1) * 66 + (x + 1)) * 48 + 32 + c;
    in1hi0[pidx] = f2u((f16)x0[i]);
    return;
  }
  i -= 12288;
  if (i < 262144) {  // fcw transpose: fcwp[cidx*6+j] = fcw[j*262144+cidx]
    float* dst = fcwp + (size_t)i * 6;
#pragma unroll
    for (int j = 0; j < 6; ++j) dst[j] = fcw[(size_t)j * 262144 + i];
  }
}

// ---- one ConvLSTM step for one layer (device body) ----
// bid in [0,256) = 2 M-blocks x 128 pixel tiles (4y x 8x); block 256 = 4 waves.
// L1: input = bhi (in1: h1@c0-31, x@c32-34). Writes d1 = in1-next, d2 = in2a.
// L2: input = bhi (in2a, 32ch) + b2hi (in2b, 64ch). Writes d1 = in2b.
template <int LAYER>
__device__ __forceinline__ void conv_body(
    int bid,
    const ushort_t* __restrict__ bhi, const ushort_t* __restrict__ b2hi,
    const ushort_t* __restrict__ wp, const float* __restrict__ bias,
    float* __restrict__ cst, float* __restrict__ hout,              // fp32 c (in-place), h
    ushort_t* __restrict__ d1hi,                                    // primary dest
    ushort_t* __restrict__ d2hi,                                    // secondary (L1 only)
    const float* __restrict__ fcwp, float* __restrict__ pose_t,     // L2 only
    const float* __restrict__ xn,                                   // L1 only: x[t+1]
    ushort_t* Bh, ushort_t* hs, float (*red)[6]) {
  constexpr int CS = (LAYER == 1) ? 72 : 104;   // LDS c-stride (bank-conflict pad)
  constexpr int NC32 = (LAYER == 1) ? 2 : 3;    // 32-channel chunks
  constexpr int NS = 9 * NC32;                  // k32 steps
  constexpr int MT = (LAYER == 1) ? 4 : 8;      // 16-row m-tiles per block
  constexpr int MTPW = (LAYER == 1) ? 1 : 2;    // m-tiles per wave
  constexpr int H = (LAYER == 1) ? 32 : 64;
  constexpr int DEPTH = 8;                      // A-frag register ring (hi only)
  constexpr int PRE = DEPTH - 1;

  const int tid = threadIdx.x;
  const int lane = tid & 63;
  const int w = tid >> 6;
  const int mb = bid & 1;
  const int ntile = bid >> 1;
  const int Y0 = (ntile >> 3) * 4;
  const int X0 = (ntile & 7) * 8;

  // ---- stage halo slab [6y][10x][C] into LDS (issued FIRST: critical path
  //      to the barrier; A-ring slots 1..7 not needed until K-steps 1..7) ----
  if (LAYER == 2) {
    for (int i = tid; i < 720; i += 256) {
      int hy = i / 120, rem = i % 120;
      int hx = rem / 12, c8 = rem % 12;
      int pos = (Y0 + hy) * 66 + X0 + hx;
      int dst = (hy * 10 + hx) * CS + c8 * 8;
      if (c8 < 4) {  // c0-31 from in2a (h1)
        *(uint4*)(&Bh[dst]) = *(const uint4*)(&bhi[pos * 32 + c8 * 8]);
      } else {       // c32-95 from in2b (h2)
        *(uint4*)(&Bh[dst]) = *(const uint4*)(&b2hi[pos * 64 + (c8 - 4) * 8]);
      }
    }
  } else {
    for (int i = tid; i < 360; i += 256) {
      int hy = i / 60, rem = i % 60;
      int hx = rem / 6, c8 = (rem % 6) * 8;
      int src = ((Y0 + hy) * 66 + X0 + hx) * 48 + c8;
      int dst = (hy * 10 + hx) * CS + c8;
      *(uint4*)(&Bh[dst]) = *(const uint4*)(&bhi[src]);
    }
    for (int i = tid; i < 120; i += 256) {  // zero-pad c 48..63 (read by frags)
      int hp = i >> 1;
      int dst = hp * CS + 48 + (i & 1) * 8;
      *(uint4*)(&Bh[dst]) = uint4{0, 0, 0, 0};
    }
  }

  // ---- A-frag register ring (weight hi only) ----
  const ushort_t* aptr[MTPW];
#pragma unroll
  for (int m = 0; m < MTPW; ++m) {
    int f = (mb * NS) * MT + (w * MTPW + m);
    aptr[m] = wp + f * 512 + lane * 8;
  }
  uint4 A[DEPTH][MTPW];
  auto loada = [&](int s) {
#pragma unroll
    for (int m = 0; m < MTPW; ++m) {
      A[s % DEPTH][m] = *(const uint4*)(aptr[m] + (size_t)s * (MT * 512));
    }
  };
#pragma unroll
  for (int s = 0; s < PRE; ++s) loada(s);
  __syncthreads();

  // ---- K-loop: A frags from registers (ring-prefetched), B frags from LDS ----
  const int n = lane & 15;
  const int q = lane >> 4;
  const int py = n >> 3, px = n & 7;

  f32x4 acc[MTPW][2];
#pragma unroll
  for (int m = 0; m < MTPW; ++m)
#pragma unroll
    for (int nt = 0; nt < 2; ++nt) acc[m][nt] = f32x4{0.f, 0.f, 0.f, 0.f};

#pragma unroll
  for (int s = 0; s < NS; ++s) {
    // rolling prefetch: writes ring slot consumed LAST iteration (WAR-bounded)
    if (s + PRE < NS) loada(s + PRE);
    const int tap = s / NC32, cc = s % NC32;
    const int ty = tap / 3, tx = tap % 3;
    const int coff = cc * 32 + q * 8;
    f16x8 bfh[2];
#pragma unroll
    for (int nt = 0; nt < 2; ++nt) {
      int hp = (py + nt * 2 + ty) * 10 + (px + tx);
      bfh[nt] = u2f(*(const uint4*)(&Bh[hp * CS + coff]));
    }
#pragma unroll
    for (int m = 0; m < MTPW; ++m) {
      f16x8 ah = u2f(A[s % DEPTH][m]);
#pragma unroll
      for (int nt = 0; nt < 2; ++nt) {
        acc[m][nt] = __builtin_amdgcn_mfma_f32_16x16x32_f16(ah, bfh[nt], acc[m][nt], 0, 0, 0);
      }
    }
  }

  // ---- LSTM cell DIRECTLY from acc (no zs LDS round-trip): lane (n,q) of
  //      m-tile mt holds gates i,f,o,g of cell (ch=mt*4+q, pixel=nt*16+n)
  //      in acc[m][nt][0..3] (C/D row = q*4+reg; pack gate = row&3). ----
  float p6[6] = {0, 0, 0, 0, 0, 0};
#pragma unroll
  for (int m = 0; m < MTPW; ++m) {
    const int ch = (w * MTPW + m) * 4 + q;   // channel within mb half
    const int hg = mb * (MT * 4) + ch;
    const float bi = bias[0 * H + hg];
    const float bf = bias[1 * H + hg];
    const float bo = bias[2 * H + hg];
    const float bg = bias[3 * H + hg];
#pragma unroll
    for (int nt = 0; nt < 2; ++nt) {
      const int pI = nt * 16 + n;
      float zi = acc[m][nt][0] + bi;
      float zf = acc[m][nt][1] + bf;
      float zo = acc[m][nt][2] + bo;
      float zg = acc[m][nt][3] + bg;
      int y = Y0 + (pI >> 3), x = X0 + (pI & 7);
      int cidx = hg * 4096 + y * 64 + x;
      float cold = cst[cidx];
      float cn = sigm(zf) * cold + sigm(zi) * tanh_fast(zg);
      float hn = sigm(zo) * tanh_fast(cn);
      cst[cidx] = cn;
      hout[cidx] = hn;
      hs[pI * 36 + ch] = f2u((f16)hn);
      if (LAYER == 2) {
#pragma unroll
        for (int j = 0; j < 6; ++j) p6[j] += hn * fcwp[(size_t)cidx * 6 + j];
      }
    }
  }
  __syncthreads();  // hs complete

  // ---- coalesced h-staging stores (plain 8B stores, full 32B granules) ----
  if (LAYER == 2) {
    int pxi = tid & 31, g = tid >> 5;   // 32 px x 8 ch-groups of 4
    int y = Y0 + (pxi >> 3), x = X0 + (pxi & 7);
    int pidx = (y + 1) * 66 + (x + 1);
    u64_t v = *(const u64_t*)&hs[pxi * 36 + g * 4];
    *(u64_t*)&d1hi[pidx * 64 + mb * 32 + g * 4] = v;   // in2b: h2
  } else {
    int t2 = tid & 127;
    int pxi = t2 & 31, g = t2 >> 5;     // 32 px x 4 ch-groups of 4
    int y = Y0 + (pxi >> 3), x = X0 + (pxi & 7);
    int pidx = (y + 1) * 66 + (x + 1);
    u64_t v = *(const u64_t*)&hs[pxi * 36 + g * 4];
    if (tid < 128) {
      *(u64_t*)&d2hi[pidx * 32 + mb * 16 + g * 4] = v; // in2a: h1
    } else {
      *(u64_t*)&d1hi[pidx * 48 + mb * 16 + g * 4] = v; // in1-next: h1 @c0
    }
    // stage x[t+1] into in1 next-parity (c32-34; granule c32-47 mb0-only)
    if (mb == 0 && tid < 32) {
      int yy = Y0 + (tid >> 3), xx = X0 + (tid & 7);
      int pidx2 = (yy + 1) * 66 + (xx + 1);
#pragma unroll
      for (int c = 0; c < 3; ++c) {
        d1hi[pidx2 * 48 + 32 + c] = f2u((f16)xn[c * 4096 + yy * 64 + xx]);
      }
    }
  }

  if (LAYER == 2) {
#pragma unroll
    for (int j = 0; j < 6; ++j)
#pragma unroll
      for (int off = 32; off > 0; off >>= 1) p6[j] += __shfl_xor(p6[j], off, 64);
    if (lane == 0)
#pragma unroll
      for (int j = 0; j < 6; ++j) red[w][j] = p6[j];
    __syncthreads();
    if (tid < 6) atomicAdd(pose_t + tid, red[0][tid] + red[1][tid] + red[2][tid] + red[3][tid]);
  }
}

// ---- fused temporal-skew kernel: blocks 0-255 = L1[t], 256-511 = L2[t-1] ----
__global__ __launch_bounds__(256, 2) void fused_step(
    int t,
    const ushort_t* __restrict__ i1rhi, ushort_t* __restrict__ i1whi,
    const ushort_t* __restrict__ i2arhi, const ushort_t* __restrict__ i2brhi,
    ushort_t* __restrict__ i2awhi, ushort_t* __restrict__ i2bwhi,
    const ushort_t* __restrict__ wp1, const ushort_t* __restrict__ wp2,
    const float* __restrict__ b1, const float* __restrict__ b2,
    float* __restrict__ c1o, float* __restrict__ h1o,
    float* __restrict__ c2o, float* __restrict__ h2o,
    const float* __restrict__ fcwp, float* __restrict__ pose_t,
    const float* __restrict__ xn) {
  // union'd shared memory: max over both roles (L2 sizes), ~15 KB
  __shared__ __align__(16) ushort_t Bh[6240];   // max(60*72, 60*104)
  __shared__ __align__(8) ushort_t hs[1152];    // 32px * 36-stride hh stage
  __shared__ float red[4][6];

  int bid = blockIdx.x;
  if (bid < 256) {
    if (t >= 128) return;
    conv_body<1>(bid, i1rhi, nullptr, wp1, b1, c1o, h1o,
                 i1whi,                 // h1 -> in1 next @c0 (+ x[t+1] @c32)
                 i2awhi,                // h1 -> in2a[t&1]
                 nullptr, nullptr, xn, Bh, hs, red);
  } else {
    if (t < 1) return;
    conv_body<2>(bid - 256, i2arhi, i2brhi, wp2, b2, c2o, h2o,
                 i2bwhi,                // h2 -> in2b[t&1]
                 nullptr,
                 fcwp, pose_t, nullptr, Bh, hs, red);
  }
}

extern "C" void kernel_launch(void* const* d_in, const int* in_sizes, int n_in, void* d_out,
                              int out_size, void* d_ws, size_t ws_size, hipStream_t stream) {
  const float* input = (const float*)d_in[0];
  const float* w1 = (const float*)d_in[1];
  const float* b1 = (const float*)d_in[2];
  const float* w2 = (const float*)d_in[3];
  const float* b2 = (const float*)d_in[4];
  const float* fcw = (const float*)d_in[5];
  const float* fcb = (const float*)d_in[6];

  float* out = (float*)d_out;
  float* pose = out;
  float* h1o = out + 768;
  float* c1o = h1o + 131072;
  float* h2o = c1o + 131072;
  float* c2o = h2o + 262144;

  ushort_t* ws = (ushort_t*)d_ws;
  ushort_t* in1hi[2] = {ws, ws + IN1SZ};
  ushort_t* ab = ws + 2 * IN1SZ;
  ushort_t* i2ahi[2] = {ab, ab + IN2ASZ};
  ushort_t* bb = ab + 2 * IN2ASZ;
  ushort_t* i2bhi[2] = {bb, bb + IN2BSZ};
  ushort_t* wp1 = ws + WP1OFF;
  ushort_t* wp2 = ws + WP2OFF;
  float* fcwp = (float*)(ws + FCWPOFF);  // 6.29 MB

  // zero state buffers (t=0 h-states + padded borders). Output region: only
  // c-states need zero (h1/h2 fully overwritten every step); zero the
  // contiguous c1|h2|c2 span, skip h1.
  hipMemsetAsync(ws, 0, (size_t)WP1OFF * 2, stream);
  hipMemsetAsync(c1o, 0, (size_t)655360 * 4, stream);
  pack_kernel<<<1219, 256, 0, stream>>>(w1, w2, fcb, input, fcw, pose, wp1, wp2,
                                        in1hi[0], fcwp);

  // K_t: L1[t] (t<128) + L2[t-1] (t>=1).
  //   L1[t]: reads in1[t&1]; writes in1[(t+1)&1] (h1@c0 + x[t+1]@c32) and in2a[t&1].
  //   L2[t-1]: reads in2a/in2b[(t-1)&1]; writes in2b[t&1].
  for (int t = 0; t <= 128; ++t) {
    int p = t & 1, pn = p ^ 1;
    int tn = (t + 1 < 128) ? t + 1 : 127;
    float* pose_t = pose + ((t > 0) ? (t - 1) * 6 : 0);
    fused_step<<<512, 256, 0, stream>>>(
        t,
        in1hi[p], in1hi[pn],
        i2ahi[pn], i2bhi[pn],   // (t-1)&1 == pn
        i2ahi[p], i2bhi[p],
        wp1, wp2, b1, b2, c1o, h1o, c2o, h2o,
        fcwp, pose_t,
        input + (size_t)tn * 12288);
  }
}